// Round 3
// baseline (465.589 us; speedup 1.0000x reference)
//
#include <hip/hip_runtime.h>
#include <cmath>

// DDSP decoder, bit-exact-phase implementation.
// R3: k_conv register-blocked (4 outputs/thread, 4-tap unroll, ds_read2
//     merging, h via scalar loads) -- load path only, arithmetic identical.
//     k_harm: exact early-break on fully-masked partials.

#define NBATCH 8
#define NT     500
#define ND     128
#define TAUD   88000
#define NPART  64
#define NBINS  256
#define NFREQ  44001
#define LCONV  1024

namespace {

constexpr float  SCALE_TA = (float)(500.0 / 88000.0);   // lin_interp scale, fp32 like jnp
constexpr float  SCALE_NF = (float)(256.0 / 44001.0);
constexpr float  TWOPI_F  = (float)6.283185307179586476925286766559;
constexpr double TWOPI_D  = 6.283185307179586476925286766559;
constexpr double INV2PI_D = 0.159154943091895335768883763373;
constexpr float  CANG     = (float)(6.283185307179586476925286766559 / 88000.0);

__device__ __forceinline__ void iparams(int j, int& i0, int& i1, float& w) {
  float jf  = (float)j;
  float src = __fsub_rn(__fmul_rn(__fadd_rn(jf, 0.5f), SCALE_TA), 0.5f);
  src = fminf(fmaxf(src, 0.0f), 499.0f);
  int a = (int)src;            // floor (src >= 0)
  i0 = a;
  i1 = (a + 1 > 499) ? 499 : (a + 1);
  w  = __fsub_rn(src, (float)a);
}

__device__ __forceinline__ float inc_val(const float* sf0, int j, float pf) {
  int i0, i1; float w;
  iparams(j, i0, i1, w);
  float fa = __fmul_rn(sf0[i0], pf);
  float fb = __fmul_rn(sf0[i1], pf);
  float fu = __fadd_rn(__fmul_rn(fa, __fsub_rn(1.0f, w)), __fmul_rn(fb, w));
  return __fdiv_rn(fu, 44100.0f);
}

// sin of the exact fp32 value x (|x| up to ~3e5), matching libm sinf
__device__ __forceinline__ float sin_ref(float x) {
  double xd = (double)x;
  double k  = rint(xd * INV2PI_D);
  double r  = fma(-k, TWOPI_D, xd);
  return sinf((float)r);
}

// ---------------- f0 (Hz) ----------------
__global__ __launch_bounds__(256) void k_f0(const float* __restrict__ f0n,
                                            float* __restrict__ f0hz,
                                            float C1, float C2) {
  int i = blockIdx.x * 256 + threadIdx.x;
  if (i < NBATCH * NT) {
    float x = __fadd_rn(__fmul_rn(f0n[i], C1), C2);
    f0hz[i] = (float)exp2((double)x);
  }
}

// ---------------- MLP heads (8 rows / block) ----------------
__global__ __launch_bounds__(256) void k_mlp(
    const float* __restrict__ z,
    const float* __restrict__ W1p, const float* __restrict__ b1p,
    const float* __restrict__ W2p, const float* __restrict__ b2p,
    const float* __restrict__ W1n, const float* __restrict__ b1n,
    const float* __restrict__ W2n, const float* __restrict__ b2n,
    float* __restrict__ amp, float* __restrict__ nmag) {
  int row0 = blockIdx.x * 8;
  int tid  = threadIdx.x;
  __shared__ float zs[8][ND];
  __shared__ float hp[8][256];
  __shared__ float hn[8][256];
  for (int i = tid; i < 8 * ND; i += 256) {
    int r = i >> 7, d = i & 127;
    zs[r][d] = z[(size_t)(row0 + r) * ND + d];
  }
  __syncthreads();
  float ap[8], an[8];
  float bp = b1p[tid], bn = b1n[tid];
#pragma unroll
  for (int r = 0; r < 8; ++r) { ap[r] = bp; an[r] = bn; }
  for (int d = 0; d < ND; ++d) {
    float w1 = W1p[d * 256 + tid];
    float w2 = W1n[d * 256 + tid];
#pragma unroll
    for (int r = 0; r < 8; ++r) {
      float zz = zs[r][d];
      ap[r] = fmaf(zz, w1, ap[r]);
      an[r] = fmaf(zz, w2, an[r]);
    }
  }
#pragma unroll
  for (int r = 0; r < 8; ++r) {
    hp[r][tid] = fmaxf(ap[r], 0.0f);
    hn[r][tid] = fmaxf(an[r], 0.0f);
  }
  __syncthreads();
  // noise-mags head (256 outputs)
  float a2[8];
  float bn2 = b2n[tid];
#pragma unroll
  for (int r = 0; r < 8; ++r) a2[r] = bn2;
  for (int h = 0; h < 256; ++h) {
    float w = W2n[h * 256 + tid];
#pragma unroll
    for (int r = 0; r < 8; ++r) a2[r] = fmaf(hn[r][h], w, a2[r]);
  }
#pragma unroll
  for (int r = 0; r < 8; ++r)
    nmag[(size_t)(row0 + r) * 256 + tid] = 1.0f / (1.0f + expf(-a2[r]));
  // amp head (64 outputs)
  if (tid < 64) {
    float a1[8];
    float bp2 = b2p[tid];
#pragma unroll
    for (int r = 0; r < 8; ++r) a1[r] = bp2;
    for (int h = 0; h < 256; ++h) {
      float w = W2p[h * 64 + tid];
#pragma unroll
      for (int r = 0; r < 8; ++r) a1[r] = fmaf(hp[r][h], w, a1[r]);
    }
#pragma unroll
    for (int r = 0; r < 8; ++r)
      amp[(size_t)(row0 + r) * 64 + tid] = 1.0f / (1.0f + expf(-a1[r]));
  }
}

// ---------------- mean over frames (== mean of lin_interp, exact) ----------------
__global__ __launch_bounds__(256) void k_mean(const float* __restrict__ nmag,
                                              float* __restrict__ mm) {
  int b = blockIdx.x, k = threadIdx.x;
  float s = 0.0f;
  for (int t = 0; t < NT; ++t) s += nmag[((size_t)b * NT + t) * 256 + k];
  mm[b * 256 + k] = s * (1.0f / 500.0f);
}

// ---------------- basis G[n][i] = sum_k hat_i(k) * cos(2 pi n k / 88000) ----------------
__global__ __launch_bounds__(256) void k_basis(float* __restrict__ G) {
  int n = blockIdx.x;       // 0..1024
  int i = threadIdx.x;      // bin 0..255
  int start = 1, end = 43999;
  if (i > 0) {
    int s0 = (int)(((float)i - 0.5f) * 171.87890625f - 0.5f) - 4;
    if (s0 > start) start = s0;
  }
  int e0 = (int)(((float)i + 1.5f) * 171.87890625f - 0.5f) + 4;
  if (e0 < end) end = e0;
  float acc = 0.0f;
  int m = (n * start) % TAUD;
  for (int k = start; k <= end; ++k) {
    float kf  = (float)k;
    float src = __fsub_rn(__fmul_rn(__fadd_rn(kf, 0.5f), SCALE_NF), 0.5f);
    src = fminf(fmaxf(src, 0.0f), 255.0f);
    int i0 = (int)src;
    float w = __fsub_rn(src, (float)i0);
    float wt = 0.0f;
    if (i0 == i) wt = __fsub_rn(1.0f, w);
    int i1 = (i0 < 255) ? i0 + 1 : 255;
    if (i1 == i) wt = __fadd_rn(wt, w);
    acc = fmaf(wt, __cosf((float)m * CANG), acc);
    m += n; if (m >= TAUD) m -= TAUD;
  }
  G[n * 256 + i] = acc;
}

// ---------------- combine: h[b][n] = (F0 +- FN + 2*sum_i mm_i G[n][i]) / N ----------------
__global__ __launch_bounds__(256) void k_hc(const float* __restrict__ mm,
                                            const float* __restrict__ G,
                                            float* __restrict__ hh) {
  int n = blockIdx.x;       // 0..1024
  int tid = threadIdx.x;
  float g = G[n * 256 + tid];
  __shared__ float red[256];
  for (int b = 0; b < NBATCH; ++b) {
    red[tid] = mm[b * 256 + tid] * g;
    __syncthreads();
    for (int st = 128; st > 0; st >>= 1) {
      if (tid < st) red[tid] += red[tid + st];
      __syncthreads();
    }
    if (tid == 0) {
      float F0 = mm[b * 256 + 0];
      float src = __fsub_rn(__fmul_rn(__fadd_rn(44000.0f, 0.5f), SCALE_NF), 0.5f);
      src = fminf(fmaxf(src, 0.0f), 255.0f);
      int i0 = (int)src;
      float w = __fsub_rn(src, (float)i0);
      int i1 = (i0 < 255) ? i0 + 1 : 255;
      float FN = __fadd_rn(__fmul_rn(mm[b * 256 + i0], __fsub_rn(1.0f, w)),
                           __fmul_rn(mm[b * 256 + i1], w));
      float tot = 2.0f * red[0] + F0 + ((n & 1) ? -FN : FN);
      hh[b * (LCONV + 1) + n] = tot * (1.0f / 88000.0f);
    }
    __syncthreads();
  }
}

// ---------------- cumsum top levels: Brent-Kung (associative_scan DAG) ----------------
__global__ __launch_bounds__(256) void k_scan_top(const float* __restrict__ f0hz,
                                                  float* __restrict__ pref4) {
  int bp = blockIdx.x;
  int b = bp >> 6, p = bp & 63;
  float pf = (float)(p + 1);
  __shared__ float sf0[NT];
  __shared__ float lev[10992];
  int tid = threadIdx.x;
  for (int i = tid; i < NT; i += 256) sf0[i] = f0hz[b * NT + i];
  __syncthreads();
  for (int m = tid; m < 5500; m += 256) {
    float v[16];
#pragma unroll
    for (int t = 0; t < 16; ++t) v[t] = inc_val(sf0, m * 16 + t, pf);
    float s1[8];
#pragma unroll
    for (int t = 0; t < 8; ++t) s1[t] = __fadd_rn(v[2 * t], v[2 * t + 1]);
    float s2[4];
#pragma unroll
    for (int t = 0; t < 4; ++t) s2[t] = __fadd_rn(s1[2 * t], s1[2 * t + 1]);
    float s3a = __fadd_rn(s2[0], s2[1]);
    float s3b = __fadd_rn(s2[2], s2[3]);
    lev[m] = __fadd_rn(s3a, s3b);
  }
  __syncthreads();
  const int sizes[13] = {5500, 2750, 1375, 687, 343, 171, 85, 42, 21, 10, 5, 2, 1};
  const int offs[13]  = {0, 5500, 8250, 9625, 10312, 10655, 10826, 10911,
                         10953, 10974, 10984, 10989, 10991};
  for (int L = 1; L < 13; ++L) {
    int n = sizes[L];
    const float* src = lev + offs[L - 1];
    float* dst = lev + offs[L];
    for (int k2 = tid; k2 < n; k2 += 256)
      dst[k2] = __fadd_rn(src[2 * k2], src[2 * k2 + 1]);
    __syncthreads();
  }
  for (int L = 11; L >= 0; --L) {
    int n = sizes[L];
    float* cur = lev + offs[L];
    const float* up = lev + offs[L + 1];
    for (int idx = 1 + tid; idx < n; idx += 256) {
      float val;
      if (idx & 1) val = up[(idx - 1) >> 1];
      else         val = __fadd_rn(up[(idx >> 1) - 1], cur[idx]);
      cur[idx] = val;
    }
    __syncthreads();
  }
  for (int m = tid; m < 5500; m += 256)
    pref4[(size_t)bp * 5500 + m] = lev[m];
}

// ---------------- fused harmonic synth ----------------
__global__ __launch_bounds__(256) void k_harm(const float* __restrict__ f0hz,
                                              const float* __restrict__ amp,
                                              const float* __restrict__ pref4,
                                              float* __restrict__ hpart) {
  int chunk = blockIdx.x, b = blockIdx.y, g = blockIdx.z;
  int tid = threadIdx.x;
  int m = chunk * 256 + tid;
  bool act = (m < 5500);
  __shared__ float sf0[NT];
  for (int i = tid; i < NT; i += 256) sf0[i] = f0hz[b * NT + i];
  __syncthreads();
  int mm_ = act ? m : 0;
  int j0 = mm_ * 16;
  float wv[16];
  unsigned damask = 0, dnmask = 0;
  int f = 0;
#pragma unroll
  for (int t = 0; t < 16; ++t) {
    int j = j0 + t;
    float jf = (float)j;
    float src = __fsub_rn(__fmul_rn(__fadd_rn(jf, 0.5f), SCALE_TA), 0.5f);
    src = fminf(fmaxf(src, 0.0f), 499.0f);
    int a = (int)src;
    if (t == 0) f = a;                 // i0 monotone nondecreasing in j
    wv[t] = __fsub_rn(src, (float)a);
    damask |= (unsigned)(a - f) << t;  // in {0,1}
    int ni = (int)__fmul_rn(jf, SCALE_TA);
    ni = ni > 499 ? 499 : ni;
    dnmask |= (unsigned)(ni - f) << t; // in {0,1}
  }
  int f1 = (f + 1 > 499) ? 499 : f + 1;
  int f2 = (f + 2 > 499) ? 499 : f + 2;
  float s0 = sf0[f], s1 = sf0[f1], s2 = sf0[f2];

  float acc[16];
#pragma unroll
  for (int t = 0; t < 16; ++t) acc[t] = 0.0f;

  for (int pp = 0; pp < 16; ++pp) {
    int p = g * 16 + pp;
    float pf = (float)(p + 1);
    float fs0 = __fmul_rn(s0, pf);
    float fs1 = __fmul_rn(s1, pf);
    // all taps select fr from {fs0, fs1}; both >= 22050 => partial fully
    // masked; products monotone in pf => all later partials masked too.
    if (!(fs0 < 22050.0f) && !(fs1 < 22050.0f)) break;
    float fs2 = __fmul_rn(s2, pf);
    size_t pbase = ((size_t)(b * NPART + p)) * 5500;
    float left = (mm_ > 0) ? pref4[pbase + mm_ - 1] : 0.0f;
    float P4 = pref4[pbase + mm_];
    float v[16];
#pragma unroll
    for (int t = 0; t < 16; ++t) {
      bool d = (damask >> t) & 1;
      float fa = d ? fs1 : fs0;
      float fb = d ? fs2 : fs1;
      float w = wv[t];
      float fu = __fadd_rn(__fmul_rn(fa, __fsub_rn(1.0f, w)), __fmul_rn(fb, w));
      v[t] = __fdiv_rn(fu, 44100.0f);
    }
    float s1t[8];
#pragma unroll
    for (int t = 0; t < 8; ++t) s1t[t] = __fadd_rn(v[2 * t], v[2 * t + 1]);
    float s2t[4];
#pragma unroll
    for (int t = 0; t < 4; ++t) s2t[t] = __fadd_rn(s1t[2 * t], s1t[2 * t + 1]);
    float s3_0 = __fadd_rn(s2t[0], s2t[1]);
    bool fz = (mm_ == 0);
    float l3_0 = fz ? s3_0 : __fadd_rn(left, s3_0);
    float l2_0 = fz ? s2t[0] : __fadd_rn(left, s2t[0]);
    float l2_1 = l3_0;
    float l2_2 = __fadd_rn(l3_0, s2t[2]);
    float l2_3 = P4;
    float l1_0 = fz ? s1t[0] : __fadd_rn(left, s1t[0]);
    float l1_1 = l2_0;
    float l1_2 = __fadd_rn(l2_0, s1t[2]);
    float l1_3 = l2_1;
    float l1_4 = __fadd_rn(l2_1, s1t[4]);
    float l1_5 = l2_2;
    float l1_6 = __fadd_rn(l2_2, s1t[6]);
    float l1_7 = l2_3;
    float ph[16];
    ph[0]  = fz ? v[0] : __fadd_rn(left, v[0]);
    ph[1]  = l1_0;
    ph[2]  = __fadd_rn(l1_0, v[2]);
    ph[3]  = l1_1;
    ph[4]  = __fadd_rn(l1_1, v[4]);
    ph[5]  = l1_2;
    ph[6]  = __fadd_rn(l1_2, v[6]);
    ph[7]  = l1_3;
    ph[8]  = __fadd_rn(l1_3, v[8]);
    ph[9]  = l1_4;
    ph[10] = __fadd_rn(l1_4, v[10]);
    ph[11] = l1_5;
    ph[12] = __fadd_rn(l1_5, v[12]);
    ph[13] = l1_6;
    ph[14] = __fadd_rn(l1_6, v[14]);
    ph[15] = l1_7;
    float ga0 = amp[((size_t)(b * NT + f)) * 64 + p];
    float ga1 = amp[((size_t)(b * NT + f1)) * 64 + p];
    float ga2 = amp[((size_t)(b * NT + f2)) * 64 + p];
#pragma unroll
    for (int t = 0; t < 16; ++t) {
      bool dn = (dnmask >> t) & 1;
      float fr = dn ? fs1 : fs0;
      if (fr < 22050.0f) {
        float x = __fmul_rn(ph[t], TWOPI_F);
        float s = sin_ref(x);
        bool d = (damask >> t) & 1;
        float lo = d ? ga1 : ga0;
        float hi = d ? ga2 : ga1;
        float w = wv[t];
        float au = __fadd_rn(__fmul_rn(lo, __fsub_rn(1.0f, w)), __fmul_rn(hi, w));
        acc[t] = __fadd_rn(acc[t], __fmul_rn(s, au));
      }
    }
  }
  if (act) {
    size_t obase = ((size_t)g * NBATCH + b) * TAUD + (size_t)j0;
#pragma unroll
    for (int t = 0; t < 16; ++t) hpart[obase + t] = acc[t];
  }
}

// ---------------- circular convolution (truncated +-LCONV) ----------------
// 4 consecutive outputs/thread, 4-tap unroll: 14 LDS values serve 16
// (tap,output) pairs via ds_read2 merging; h via uniform (scalar) loads.
// Per-accumulator fma chain remains ascending-d, identical ops -> bit-exact.
__global__ __launch_bounds__(256) void k_conv(const float* __restrict__ noise,
                                              const float* __restrict__ hh,
                                              float* __restrict__ ynz) {
  int b = blockIdx.y;
  int t0 = blockIdx.x * 1024;
  int tid = threadIdx.x;
  __shared__ float xs[3072];          // [t0-1024, t0+2047]
  const float* hb = hh + b * (LCONV + 1);
  for (int i = tid; i < 3072; i += 256) {
    int j = t0 - LCONV + i;
    if (j < 0) j += TAUD;
    else if (j >= TAUD) j -= TAUD;
    xs[i] = noise[(size_t)b * TAUD + j];
  }
  __syncthreads();
  int tb = tid * 4;
  float h0 = hb[0];
  float a0 = h0 * xs[LCONV + tb];
  float a1 = h0 * xs[LCONV + tb + 1];
  float a2 = h0 * xs[LCONV + tb + 2];
  float a3 = h0 * xs[LCONV + tb + 3];
  for (int d = 1; d <= LCONV; d += 4) {
    float hc0 = hb[d], hc1 = hb[d + 1], hc2 = hb[d + 2], hc3 = hb[d + 3];
    float xm[7], xp[7];
    int bm = LCONV + tb - d - 3;
    int bp_ = LCONV + tb + d;
#pragma unroll
    for (int u = 0; u < 7; ++u) { xm[u] = xs[bm + u]; xp[u] = xs[bp_ + u]; }
    a0 = fmaf(hc0, xm[3] + xp[0], a0);
    a0 = fmaf(hc1, xm[2] + xp[1], a0);
    a0 = fmaf(hc2, xm[1] + xp[2], a0);
    a0 = fmaf(hc3, xm[0] + xp[3], a0);
    a1 = fmaf(hc0, xm[4] + xp[1], a1);
    a1 = fmaf(hc1, xm[3] + xp[2], a1);
    a1 = fmaf(hc2, xm[2] + xp[3], a1);
    a1 = fmaf(hc3, xm[1] + xp[4], a1);
    a2 = fmaf(hc0, xm[5] + xp[2], a2);
    a2 = fmaf(hc1, xm[4] + xp[3], a2);
    a2 = fmaf(hc2, xm[3] + xp[4], a2);
    a2 = fmaf(hc3, xm[2] + xp[5], a2);
    a3 = fmaf(hc0, xm[6] + xp[3], a3);
    a3 = fmaf(hc1, xm[5] + xp[4], a3);
    a3 = fmaf(hc2, xm[4] + xp[5], a3);
    a3 = fmaf(hc3, xm[3] + xp[6], a3);
  }
  int t = t0 + tb;
  if (t < TAUD) {                     // TAUD%4==0 -> all 4 valid together
    float4 o = make_float4(a0 * 0.1f, a1 * 0.1f, a2 * 0.1f, a3 * 0.1f);
    *reinterpret_cast<float4*>(&ynz[(size_t)b * TAUD + t]) = o;
  }
}

// ---------------- final mix ----------------
__global__ __launch_bounds__(256) void k_final(const float* __restrict__ hpart,
                                               const float* __restrict__ ynz,
                                               const float* __restrict__ loud,
                                               float* __restrict__ out) {
  int idx = blockIdx.x * 256 + threadIdx.x;
  if (idx >= NBATCH * TAUD) return;
  int b = idx / TAUD, j = idx - b * TAUD;
  int i0, i1; float w;
  iparams(j, i0, i1, w);
  float env = __fadd_rn(__fmul_rn(loud[b * NT + i0], __fsub_rn(1.0f, w)),
                        __fmul_rn(loud[b * NT + i1], w));
  const size_t S = (size_t)NBATCH * TAUD;
  float hsum = __fadd_rn(__fadd_rn(__fadd_rn(hpart[idx], hpart[S + idx]),
                                   hpart[2 * S + idx]),
                         hpart[3 * S + idx]);
  out[idx] = __fmul_rn(__fadd_rn(hsum, ynz[idx]), env);
}

}  // namespace

extern "C" void kernel_launch(void* const* d_in, const int* in_sizes, int n_in,
                              void* d_out, int out_size, void* d_ws, size_t ws_size,
                              hipStream_t stream) {
  const float* z    = (const float*)d_in[0];
  const float* f0n  = (const float*)d_in[1];
  const float* loud = (const float*)d_in[2];
  const float* nz   = (const float*)d_in[3];
  const float* W1p  = (const float*)d_in[4];
  const float* b1p  = (const float*)d_in[5];
  const float* W2p  = (const float*)d_in[6];
  const float* b2p  = (const float*)d_in[7];
  const float* W1n  = (const float*)d_in[8];
  const float* b1n  = (const float*)d_in[9];
  const float* W2n  = (const float*)d_in[10];
  const float* b2n  = (const float*)d_in[11];
  float* out = (float*)d_out;
  float* ws  = (float*)d_ws;

  size_t off = 0;
  float* amp   = ws + off; off += (size_t)NBATCH * NT * NPART;      // 256,000
  float* nmag  = ws + off; off += (size_t)NBATCH * NT * NBINS;      // 1,024,000
  float* f0hz  = ws + off; off += (size_t)NBATCH * NT;              // 4,000
  float* mmw   = ws + off; off += (size_t)NBATCH * NBINS;           // 2,048
  float* G     = ws + off; off += (size_t)(LCONV + 1) * NBINS;      // 262,400
  float* hh    = ws + off; off += (size_t)NBATCH * (LCONV + 1);     // 8,200
  float* ynz   = ws + off; off += (size_t)NBATCH * TAUD;            // 704,000
  float* pref4 = ws + off; off += (size_t)NBATCH * NPART * 5500;    // 2,816,000
  float* hpart = ws + off; off += (size_t)4 * NBATCH * TAUD;        // 2,816,000
  (void)ws_size; (void)in_sizes; (void)n_in; (void)out_size;        // ~31.2 MB total

  double HI = log2(2093.0), LO = log2(32.7);
  float C1 = (float)(HI - LO), C2 = (float)LO;

  k_basis<<<LCONV + 1, 256, 0, stream>>>(G);
  k_f0<<<(NBATCH * NT + 255) / 256, 256, 0, stream>>>(f0n, f0hz, C1, C2);
  k_mlp<<<(NBATCH * NT) / 8, 256, 0, stream>>>(z, W1p, b1p, W2p, b2p,
                                               W1n, b1n, W2n, b2n, amp, nmag);
  k_mean<<<NBATCH, 256, 0, stream>>>(nmag, mmw);
  k_hc<<<LCONV + 1, 256, 0, stream>>>(mmw, G, hh);
  k_scan_top<<<NBATCH * NPART, 256, 0, stream>>>(f0hz, pref4);
  dim3 gh(22, NBATCH, 4);
  k_harm<<<gh, 256, 0, stream>>>(f0hz, amp, pref4, hpart);
  dim3 gc((TAUD + 1023) / 1024, NBATCH);
  k_conv<<<gc, 256, 0, stream>>>(nz, hh, ynz);
  k_final<<<(NBATCH * TAUD + 255) / 256, 256, 0, stream>>>(hpart, ynz, loud, out);
}

// Round 4
// 409.396 us; speedup vs baseline: 1.1373x; 1.1373x over previous
//
#include <hip/hip_runtime.h>
#include <cmath>

// DDSP decoder, bit-exact-phase implementation.
// R4: k_conv rebuilt with aligned float4 LDS tiles (4 outputs/thread,
//     4-tap groups, 4x ds_read_b128 lane-consecutive + 1 broadcast b128
//     per 16 pairs). Accumulation order identical to R1/R2 -> bit-exact.

#define NBATCH 8
#define NT     500
#define ND     128
#define TAUD   88000
#define NPART  64
#define NBINS  256
#define NFREQ  44001
#define LCONV  1024

namespace {

constexpr float  SCALE_TA = (float)(500.0 / 88000.0);   // lin_interp scale, fp32 like jnp
constexpr float  SCALE_NF = (float)(256.0 / 44001.0);
constexpr float  TWOPI_F  = (float)6.283185307179586476925286766559;
constexpr double TWOPI_D  = 6.283185307179586476925286766559;
constexpr double INV2PI_D = 0.159154943091895335768883763373;
constexpr float  CANG     = (float)(6.283185307179586476925286766559 / 88000.0);

__device__ __forceinline__ void iparams(int j, int& i0, int& i1, float& w) {
  float jf  = (float)j;
  float src = __fsub_rn(__fmul_rn(__fadd_rn(jf, 0.5f), SCALE_TA), 0.5f);
  src = fminf(fmaxf(src, 0.0f), 499.0f);
  int a = (int)src;            // floor (src >= 0)
  i0 = a;
  i1 = (a + 1 > 499) ? 499 : (a + 1);
  w  = __fsub_rn(src, (float)a);
}

__device__ __forceinline__ float inc_val(const float* sf0, int j, float pf) {
  int i0, i1; float w;
  iparams(j, i0, i1, w);
  float fa = __fmul_rn(sf0[i0], pf);
  float fb = __fmul_rn(sf0[i1], pf);
  float fu = __fadd_rn(__fmul_rn(fa, __fsub_rn(1.0f, w)), __fmul_rn(fb, w));
  return __fdiv_rn(fu, 44100.0f);
}

// sin of the exact fp32 value x (|x| up to ~3e5), matching libm sinf
__device__ __forceinline__ float sin_ref(float x) {
  double xd = (double)x;
  double k  = rint(xd * INV2PI_D);
  double r  = fma(-k, TWOPI_D, xd);
  return sinf((float)r);
}

// ---------------- f0 (Hz) ----------------
__global__ __launch_bounds__(256) void k_f0(const float* __restrict__ f0n,
                                            float* __restrict__ f0hz,
                                            float C1, float C2) {
  int i = blockIdx.x * 256 + threadIdx.x;
  if (i < NBATCH * NT) {
    float x = __fadd_rn(__fmul_rn(f0n[i], C1), C2);
    f0hz[i] = (float)exp2((double)x);
  }
}

// ---------------- MLP heads (8 rows / block) ----------------
__global__ __launch_bounds__(256) void k_mlp(
    const float* __restrict__ z,
    const float* __restrict__ W1p, const float* __restrict__ b1p,
    const float* __restrict__ W2p, const float* __restrict__ b2p,
    const float* __restrict__ W1n, const float* __restrict__ b1n,
    const float* __restrict__ W2n, const float* __restrict__ b2n,
    float* __restrict__ amp, float* __restrict__ nmag) {
  int row0 = blockIdx.x * 8;
  int tid  = threadIdx.x;
  __shared__ float zs[8][ND];
  __shared__ float hp[8][256];
  __shared__ float hn[8][256];
  for (int i = tid; i < 8 * ND; i += 256) {
    int r = i >> 7, d = i & 127;
    zs[r][d] = z[(size_t)(row0 + r) * ND + d];
  }
  __syncthreads();
  float ap[8], an[8];
  float bp = b1p[tid], bn = b1n[tid];
#pragma unroll
  for (int r = 0; r < 8; ++r) { ap[r] = bp; an[r] = bn; }
  for (int d = 0; d < ND; ++d) {
    float w1 = W1p[d * 256 + tid];
    float w2 = W1n[d * 256 + tid];
#pragma unroll
    for (int r = 0; r < 8; ++r) {
      float zz = zs[r][d];
      ap[r] = fmaf(zz, w1, ap[r]);
      an[r] = fmaf(zz, w2, an[r]);
    }
  }
#pragma unroll
  for (int r = 0; r < 8; ++r) {
    hp[r][tid] = fmaxf(ap[r], 0.0f);
    hn[r][tid] = fmaxf(an[r], 0.0f);
  }
  __syncthreads();
  // noise-mags head (256 outputs)
  float a2[8];
  float bn2 = b2n[tid];
#pragma unroll
  for (int r = 0; r < 8; ++r) a2[r] = bn2;
  for (int h = 0; h < 256; ++h) {
    float w = W2n[h * 256 + tid];
#pragma unroll
    for (int r = 0; r < 8; ++r) a2[r] = fmaf(hn[r][h], w, a2[r]);
  }
#pragma unroll
  for (int r = 0; r < 8; ++r)
    nmag[(size_t)(row0 + r) * 256 + tid] = 1.0f / (1.0f + expf(-a2[r]));
  // amp head (64 outputs)
  if (tid < 64) {
    float a1[8];
    float bp2 = b2p[tid];
#pragma unroll
    for (int r = 0; r < 8; ++r) a1[r] = bp2;
    for (int h = 0; h < 256; ++h) {
      float w = W2p[h * 64 + tid];
#pragma unroll
      for (int r = 0; r < 8; ++r) a1[r] = fmaf(hp[r][h], w, a1[r]);
    }
#pragma unroll
    for (int r = 0; r < 8; ++r)
      amp[(size_t)(row0 + r) * 64 + tid] = 1.0f / (1.0f + expf(-a1[r]));
  }
}

// ---------------- mean over frames (== mean of lin_interp, exact) ----------------
__global__ __launch_bounds__(256) void k_mean(const float* __restrict__ nmag,
                                              float* __restrict__ mm) {
  int b = blockIdx.x, k = threadIdx.x;
  float s = 0.0f;
  for (int t = 0; t < NT; ++t) s += nmag[((size_t)b * NT + t) * 256 + k];
  mm[b * 256 + k] = s * (1.0f / 500.0f);
}

// ---------------- basis G[n][i] = sum_k hat_i(k) * cos(2 pi n k / 88000) ----------------
__global__ __launch_bounds__(256) void k_basis(float* __restrict__ G) {
  int n = blockIdx.x;       // 0..1024
  int i = threadIdx.x;      // bin 0..255
  int start = 1, end = 43999;
  if (i > 0) {
    int s0 = (int)(((float)i - 0.5f) * 171.87890625f - 0.5f) - 4;
    if (s0 > start) start = s0;
  }
  int e0 = (int)(((float)i + 1.5f) * 171.87890625f - 0.5f) + 4;
  if (e0 < end) end = e0;
  float acc = 0.0f;
  int m = (n * start) % TAUD;
  for (int k = start; k <= end; ++k) {
    float kf  = (float)k;
    float src = __fsub_rn(__fmul_rn(__fadd_rn(kf, 0.5f), SCALE_NF), 0.5f);
    src = fminf(fmaxf(src, 0.0f), 255.0f);
    int i0 = (int)src;
    float w = __fsub_rn(src, (float)i0);
    float wt = 0.0f;
    if (i0 == i) wt = __fsub_rn(1.0f, w);
    int i1 = (i0 < 255) ? i0 + 1 : 255;
    if (i1 == i) wt = __fadd_rn(wt, w);
    acc = fmaf(wt, __cosf((float)m * CANG), acc);
    m += n; if (m >= TAUD) m -= TAUD;
  }
  G[n * 256 + i] = acc;
}

// ---------------- combine: h[b][n] = (F0 +- FN + 2*sum_i mm_i G[n][i]) / N ----------------
__global__ __launch_bounds__(256) void k_hc(const float* __restrict__ mm,
                                            const float* __restrict__ G,
                                            float* __restrict__ hh) {
  int n = blockIdx.x;       // 0..1024
  int tid = threadIdx.x;
  float g = G[n * 256 + tid];
  __shared__ float red[256];
  for (int b = 0; b < NBATCH; ++b) {
    red[tid] = mm[b * 256 + tid] * g;
    __syncthreads();
    for (int st = 128; st > 0; st >>= 1) {
      if (tid < st) red[tid] += red[tid + st];
      __syncthreads();
    }
    if (tid == 0) {
      float F0 = mm[b * 256 + 0];
      float src = __fsub_rn(__fmul_rn(__fadd_rn(44000.0f, 0.5f), SCALE_NF), 0.5f);
      src = fminf(fmaxf(src, 0.0f), 255.0f);
      int i0 = (int)src;
      float w = __fsub_rn(src, (float)i0);
      int i1 = (i0 < 255) ? i0 + 1 : 255;
      float FN = __fadd_rn(__fmul_rn(mm[b * 256 + i0], __fsub_rn(1.0f, w)),
                           __fmul_rn(mm[b * 256 + i1], w));
      float tot = 2.0f * red[0] + F0 + ((n & 1) ? -FN : FN);
      hh[b * (LCONV + 1) + n] = tot * (1.0f / 88000.0f);
    }
    __syncthreads();
  }
}

// ---------------- cumsum top levels: Brent-Kung (associative_scan DAG) ----------------
__global__ __launch_bounds__(256) void k_scan_top(const float* __restrict__ f0hz,
                                                  float* __restrict__ pref4) {
  int bp = blockIdx.x;
  int b = bp >> 6, p = bp & 63;
  float pf = (float)(p + 1);
  __shared__ float sf0[NT];
  __shared__ float lev[10992];
  int tid = threadIdx.x;
  for (int i = tid; i < NT; i += 256) sf0[i] = f0hz[b * NT + i];
  __syncthreads();
  for (int m = tid; m < 5500; m += 256) {
    float v[16];
#pragma unroll
    for (int t = 0; t < 16; ++t) v[t] = inc_val(sf0, m * 16 + t, pf);
    float s1[8];
#pragma unroll
    for (int t = 0; t < 8; ++t) s1[t] = __fadd_rn(v[2 * t], v[2 * t + 1]);
    float s2[4];
#pragma unroll
    for (int t = 0; t < 4; ++t) s2[t] = __fadd_rn(s1[2 * t], s1[2 * t + 1]);
    float s3a = __fadd_rn(s2[0], s2[1]);
    float s3b = __fadd_rn(s2[2], s2[3]);
    lev[m] = __fadd_rn(s3a, s3b);
  }
  __syncthreads();
  const int sizes[13] = {5500, 2750, 1375, 687, 343, 171, 85, 42, 21, 10, 5, 2, 1};
  const int offs[13]  = {0, 5500, 8250, 9625, 10312, 10655, 10826, 10911,
                         10953, 10974, 10984, 10989, 10991};
  for (int L = 1; L < 13; ++L) {
    int n = sizes[L];
    const float* src = lev + offs[L - 1];
    float* dst = lev + offs[L];
    for (int k2 = tid; k2 < n; k2 += 256)
      dst[k2] = __fadd_rn(src[2 * k2], src[2 * k2 + 1]);
    __syncthreads();
  }
  for (int L = 11; L >= 0; --L) {
    int n = sizes[L];
    float* cur = lev + offs[L];
    const float* up = lev + offs[L + 1];
    for (int idx = 1 + tid; idx < n; idx += 256) {
      float val;
      if (idx & 1) val = up[(idx - 1) >> 1];
      else         val = __fadd_rn(up[(idx >> 1) - 1], cur[idx]);
      cur[idx] = val;
    }
    __syncthreads();
  }
  for (int m = tid; m < 5500; m += 256)
    pref4[(size_t)bp * 5500 + m] = lev[m];
}

// ---------------- fused harmonic synth ----------------
__global__ __launch_bounds__(256) void k_harm(const float* __restrict__ f0hz,
                                              const float* __restrict__ amp,
                                              const float* __restrict__ pref4,
                                              float* __restrict__ hpart) {
  int chunk = blockIdx.x, b = blockIdx.y, g = blockIdx.z;
  int tid = threadIdx.x;
  int m = chunk * 256 + tid;
  bool act = (m < 5500);
  __shared__ float sf0[NT];
  for (int i = tid; i < NT; i += 256) sf0[i] = f0hz[b * NT + i];
  __syncthreads();
  int mm_ = act ? m : 0;
  int j0 = mm_ * 16;
  float wv[16];
  unsigned damask = 0, dnmask = 0;
  int f = 0;
#pragma unroll
  for (int t = 0; t < 16; ++t) {
    int j = j0 + t;
    float jf = (float)j;
    float src = __fsub_rn(__fmul_rn(__fadd_rn(jf, 0.5f), SCALE_TA), 0.5f);
    src = fminf(fmaxf(src, 0.0f), 499.0f);
    int a = (int)src;
    if (t == 0) f = a;                 // i0 monotone nondecreasing in j
    wv[t] = __fsub_rn(src, (float)a);
    damask |= (unsigned)(a - f) << t;  // in {0,1}
    int ni = (int)__fmul_rn(jf, SCALE_TA);
    ni = ni > 499 ? 499 : ni;
    dnmask |= (unsigned)(ni - f) << t; // in {0,1}
  }
  int f1 = (f + 1 > 499) ? 499 : f + 1;
  int f2 = (f + 2 > 499) ? 499 : f + 2;
  float s0 = sf0[f], s1 = sf0[f1], s2 = sf0[f2];

  float acc[16];
#pragma unroll
  for (int t = 0; t < 16; ++t) acc[t] = 0.0f;

  for (int pp = 0; pp < 16; ++pp) {
    int p = g * 16 + pp;
    float pf = (float)(p + 1);
    float fs0 = __fmul_rn(s0, pf);
    float fs1 = __fmul_rn(s1, pf);
    if (!(fs0 < 22050.0f) && !(fs1 < 22050.0f)) break;
    float fs2 = __fmul_rn(s2, pf);
    size_t pbase = ((size_t)(b * NPART + p)) * 5500;
    float left = (mm_ > 0) ? pref4[pbase + mm_ - 1] : 0.0f;
    float P4 = pref4[pbase + mm_];
    float v[16];
#pragma unroll
    for (int t = 0; t < 16; ++t) {
      bool d = (damask >> t) & 1;
      float fa = d ? fs1 : fs0;
      float fb = d ? fs2 : fs1;
      float w = wv[t];
      float fu = __fadd_rn(__fmul_rn(fa, __fsub_rn(1.0f, w)), __fmul_rn(fb, w));
      v[t] = __fdiv_rn(fu, 44100.0f);
    }
    float s1t[8];
#pragma unroll
    for (int t = 0; t < 8; ++t) s1t[t] = __fadd_rn(v[2 * t], v[2 * t + 1]);
    float s2t[4];
#pragma unroll
    for (int t = 0; t < 4; ++t) s2t[t] = __fadd_rn(s1t[2 * t], s1t[2 * t + 1]);
    float s3_0 = __fadd_rn(s2t[0], s2t[1]);
    bool fz = (mm_ == 0);
    float l3_0 = fz ? s3_0 : __fadd_rn(left, s3_0);
    float l2_0 = fz ? s2t[0] : __fadd_rn(left, s2t[0]);
    float l2_1 = l3_0;
    float l2_2 = __fadd_rn(l3_0, s2t[2]);
    float l2_3 = P4;
    float l1_0 = fz ? s1t[0] : __fadd_rn(left, s1t[0]);
    float l1_1 = l2_0;
    float l1_2 = __fadd_rn(l2_0, s1t[2]);
    float l1_3 = l2_1;
    float l1_4 = __fadd_rn(l2_1, s1t[4]);
    float l1_5 = l2_2;
    float l1_6 = __fadd_rn(l2_2, s1t[6]);
    float l1_7 = l2_3;
    float ph[16];
    ph[0]  = fz ? v[0] : __fadd_rn(left, v[0]);
    ph[1]  = l1_0;
    ph[2]  = __fadd_rn(l1_0, v[2]);
    ph[3]  = l1_1;
    ph[4]  = __fadd_rn(l1_1, v[4]);
    ph[5]  = l1_2;
    ph[6]  = __fadd_rn(l1_2, v[6]);
    ph[7]  = l1_3;
    ph[8]  = __fadd_rn(l1_3, v[8]);
    ph[9]  = l1_4;
    ph[10] = __fadd_rn(l1_4, v[10]);
    ph[11] = l1_5;
    ph[12] = __fadd_rn(l1_5, v[12]);
    ph[13] = l1_6;
    ph[14] = __fadd_rn(l1_6, v[14]);
    ph[15] = l1_7;
    float ga0 = amp[((size_t)(b * NT + f)) * 64 + p];
    float ga1 = amp[((size_t)(b * NT + f1)) * 64 + p];
    float ga2 = amp[((size_t)(b * NT + f2)) * 64 + p];
#pragma unroll
    for (int t = 0; t < 16; ++t) {
      bool dn = (dnmask >> t) & 1;
      float fr = dn ? fs1 : fs0;
      if (fr < 22050.0f) {
        float x = __fmul_rn(ph[t], TWOPI_F);
        float s = sin_ref(x);
        bool d = (damask >> t) & 1;
        float lo = d ? ga1 : ga0;
        float hi = d ? ga2 : ga1;
        float w = wv[t];
        float au = __fadd_rn(__fmul_rn(lo, __fsub_rn(1.0f, w)), __fmul_rn(hi, w));
        acc[t] = __fadd_rn(acc[t], __fmul_rn(s, au));
      }
    }
  }
  if (act) {
    size_t obase = ((size_t)g * NBATCH + b) * TAUD + (size_t)j0;
#pragma unroll
    for (int t = 0; t < 16; ++t) hpart[obase + t] = acc[t];
  }
}

// ---------------- circular convolution (truncated +-LCONV) ----------------
// 4 outputs/thread, 4-tap groups. All LDS x-reads are aligned float4 with
// lane-consecutive 16B addresses (conflict-free ds_read_b128); h read as one
// broadcast b128 per group. Accumulation order identical to R1/R2 (ascending
// d, fmaf(h, xm+xp, acc)) -> bit-exact.
__global__ __launch_bounds__(256) void k_conv(const float* __restrict__ noise,
                                              const float* __restrict__ hh,
                                              float* __restrict__ ynz) {
  int b = blockIdx.y;
  int t0 = blockIdx.x * 1024;
  int tid = threadIdx.x;
  __shared__ float4 xs4[768];         // xs[3072] = x[t0-1024 .. t0+2047]
  __shared__ float4 hs4[256];         // h[1..1024], shifted
  float* xs = (float*)xs4;
  float* hsh = (float*)hs4;
  const float* hb = hh + b * (LCONV + 1);
  for (int i = tid; i < 3072; i += 256) {
    int j = t0 - 1024 + i;
    if (j < 0) j += TAUD;
    else if (j >= TAUD) j -= TAUD;
    xs[i] = noise[(size_t)b * TAUD + j];
  }
  for (int i = tid; i < 1024; i += 256) hsh[i] = hb[1 + i];
  __syncthreads();
  int tb = tid * 4;
  int base = tb + 1024;               // xs index of output t0+tb
  int iq = base >> 2;                 // quad index (lane-consecutive)
  float h0 = hb[0];
  float a0 = h0 * xs[base];
  float a1 = h0 * xs[base + 1];
  float a2 = h0 * xs[base + 2];
  float a3 = h0 * xs[base + 3];
  for (int g = 0; g < 256; ++g) {     // taps d = 4g+1 .. 4g+4
    float4 hq  = hs4[g];              // broadcast
    float4 qm0 = xs4[iq - g - 1];     // m[0..3] = x[base-4g-4 ..]
    float4 qm1 = xs4[iq - g];         // m[4..7]
    float4 qp0 = xs4[iq + g];         // p[0..3] = x[base+4g ..]
    float4 qp1 = xs4[iq + g + 1];     // p[4..7]
    float m0 = qm0.x, m1 = qm0.y, m2 = qm0.z, m3 = qm0.w;
    float m4 = qm1.x, m5 = qm1.y, m6 = qm1.z, m7 = qm1.w;
    float p1 = qp0.y, p2 = qp0.z, p3 = qp0.w;
    float p4 = qp1.x, p5 = qp1.y, p6 = qp1.z, p7 = qp1.w;
    // output k, tap d=4g+1+dd: xm = m[k+3-dd], xp = p[k+1+dd], dd ascending
    a0 = fmaf(hq.x, m3 + p1, a0);
    a0 = fmaf(hq.y, m2 + p2, a0);
    a0 = fmaf(hq.z, m1 + p3, a0);
    a0 = fmaf(hq.w, m0 + p4, a0);
    a1 = fmaf(hq.x, m4 + p2, a1);
    a1 = fmaf(hq.y, m3 + p3, a1);
    a1 = fmaf(hq.z, m2 + p4, a1);
    a1 = fmaf(hq.w, m1 + p5, a1);
    a2 = fmaf(hq.x, m5 + p3, a2);
    a2 = fmaf(hq.y, m4 + p4, a2);
    a2 = fmaf(hq.z, m3 + p5, a2);
    a2 = fmaf(hq.w, m2 + p6, a2);
    a3 = fmaf(hq.x, m6 + p4, a3);
    a3 = fmaf(hq.y, m5 + p5, a3);
    a3 = fmaf(hq.z, m4 + p6, a3);
    a3 = fmaf(hq.w, m3 + p7, a3);
  }
  int t = t0 + tb;
  if (t < TAUD) {                     // TAUD%4==0 -> all 4 valid together
    float4 o = make_float4(a0 * 0.1f, a1 * 0.1f, a2 * 0.1f, a3 * 0.1f);
    *reinterpret_cast<float4*>(&ynz[(size_t)b * TAUD + t]) = o;
  }
}

// ---------------- final mix ----------------
__global__ __launch_bounds__(256) void k_final(const float* __restrict__ hpart,
                                               const float* __restrict__ ynz,
                                               const float* __restrict__ loud,
                                               float* __restrict__ out) {
  int idx = blockIdx.x * 256 + threadIdx.x;
  if (idx >= NBATCH * TAUD) return;
  int b = idx / TAUD, j = idx - b * TAUD;
  int i0, i1; float w;
  iparams(j, i0, i1, w);
  float env = __fadd_rn(__fmul_rn(loud[b * NT + i0], __fsub_rn(1.0f, w)),
                        __fmul_rn(loud[b * NT + i1], w));
  const size_t S = (size_t)NBATCH * TAUD;
  float hsum = __fadd_rn(__fadd_rn(__fadd_rn(hpart[idx], hpart[S + idx]),
                                   hpart[2 * S + idx]),
                         hpart[3 * S + idx]);
  out[idx] = __fmul_rn(__fadd_rn(hsum, ynz[idx]), env);
}

}  // namespace

extern "C" void kernel_launch(void* const* d_in, const int* in_sizes, int n_in,
                              void* d_out, int out_size, void* d_ws, size_t ws_size,
                              hipStream_t stream) {
  const float* z    = (const float*)d_in[0];
  const float* f0n  = (const float*)d_in[1];
  const float* loud = (const float*)d_in[2];
  const float* nz   = (const float*)d_in[3];
  const float* W1p  = (const float*)d_in[4];
  const float* b1p  = (const float*)d_in[5];
  const float* W2p  = (const float*)d_in[6];
  const float* b2p  = (const float*)d_in[7];
  const float* W1n  = (const float*)d_in[8];
  const float* b1n  = (const float*)d_in[9];
  const float* W2n  = (const float*)d_in[10];
  const float* b2n  = (const float*)d_in[11];
  float* out = (float*)d_out;
  float* ws  = (float*)d_ws;

  size_t off = 0;
  float* amp   = ws + off; off += (size_t)NBATCH * NT * NPART;      // 256,000
  float* nmag  = ws + off; off += (size_t)NBATCH * NT * NBINS;      // 1,024,000
  float* f0hz  = ws + off; off += (size_t)NBATCH * NT;              // 4,000
  float* mmw   = ws + off; off += (size_t)NBATCH * NBINS;           // 2,048
  float* G     = ws + off; off += (size_t)(LCONV + 1) * NBINS;      // 262,400
  float* hh    = ws + off; off += (size_t)NBATCH * (LCONV + 1);     // 8,200
  float* ynz   = ws + off; off += (size_t)NBATCH * TAUD;            // 704,000
  float* pref4 = ws + off; off += (size_t)NBATCH * NPART * 5500;    // 2,816,000
  float* hpart = ws + off; off += (size_t)4 * NBATCH * TAUD;        // 2,816,000
  (void)ws_size; (void)in_sizes; (void)n_in; (void)out_size;        // ~31.2 MB total

  double HI = log2(2093.0), LO = log2(32.7);
  float C1 = (float)(HI - LO), C2 = (float)LO;

  k_basis<<<LCONV + 1, 256, 0, stream>>>(G);
  k_f0<<<(NBATCH * NT + 255) / 256, 256, 0, stream>>>(f0n, f0hz, C1, C2);
  k_mlp<<<(NBATCH * NT) / 8, 256, 0, stream>>>(z, W1p, b1p, W2p, b2p,
                                               W1n, b1n, W2n, b2n, amp, nmag);
  k_mean<<<NBATCH, 256, 0, stream>>>(nmag, mmw);
  k_hc<<<LCONV + 1, 256, 0, stream>>>(mmw, G, hh);
  k_scan_top<<<NBATCH * NPART, 256, 0, stream>>>(f0hz, pref4);
  dim3 gh(22, NBATCH, 4);
  k_harm<<<gh, 256, 0, stream>>>(f0hz, amp, pref4, hpart);
  dim3 gc((TAUD + 1023) / 1024, NBATCH);
  k_conv<<<gc, 256, 0, stream>>>(nz, hh, ynz);
  k_final<<<(NBATCH * TAUD + 255) / 256, 256, 0, stream>>>(hpart, ynz, loud, out);
}

// Round 5
// 332.833 us; speedup vs baseline: 1.3989x; 1.2300x over previous
//
#include <hip/hip_runtime.h>
#include <cmath>

// DDSP decoder, bit-exact-phase implementation.
// R5: k_conv with SoA 4-plane LDS layout (plane[c][k] = x[4k+c], stride 776)
//     -> every LDS read is stride-1-lane b32, conflict-free even if the
//     compiler scalarizes. 8 taps x 4 outputs per group. Accumulation order
//     identical to R1/R2 (ascending d, fmaf(h, xm+xp, acc)) -> bit-exact.

#define NBATCH 8
#define NT     500
#define ND     128
#define TAUD   88000
#define NPART  64
#define NBINS  256
#define NFREQ  44001
#define LCONV  1024

namespace {

constexpr float  SCALE_TA = (float)(500.0 / 88000.0);   // lin_interp scale, fp32 like jnp
constexpr float  SCALE_NF = (float)(256.0 / 44001.0);
constexpr float  TWOPI_F  = (float)6.283185307179586476925286766559;
constexpr double TWOPI_D  = 6.283185307179586476925286766559;
constexpr double INV2PI_D = 0.159154943091895335768883763373;
constexpr float  CANG     = (float)(6.283185307179586476925286766559 / 88000.0);

__device__ __forceinline__ void iparams(int j, int& i0, int& i1, float& w) {
  float jf  = (float)j;
  float src = __fsub_rn(__fmul_rn(__fadd_rn(jf, 0.5f), SCALE_TA), 0.5f);
  src = fminf(fmaxf(src, 0.0f), 499.0f);
  int a = (int)src;            // floor (src >= 0)
  i0 = a;
  i1 = (a + 1 > 499) ? 499 : (a + 1);
  w  = __fsub_rn(src, (float)a);
}

__device__ __forceinline__ float inc_val(const float* sf0, int j, float pf) {
  int i0, i1; float w;
  iparams(j, i0, i1, w);
  float fa = __fmul_rn(sf0[i0], pf);
  float fb = __fmul_rn(sf0[i1], pf);
  float fu = __fadd_rn(__fmul_rn(fa, __fsub_rn(1.0f, w)), __fmul_rn(fb, w));
  return __fdiv_rn(fu, 44100.0f);
}

// sin of the exact fp32 value x (|x| up to ~3e5), matching libm sinf
__device__ __forceinline__ float sin_ref(float x) {
  double xd = (double)x;
  double k  = rint(xd * INV2PI_D);
  double r  = fma(-k, TWOPI_D, xd);
  return sinf((float)r);
}

// ---------------- f0 (Hz) ----------------
__global__ __launch_bounds__(256) void k_f0(const float* __restrict__ f0n,
                                            float* __restrict__ f0hz,
                                            float C1, float C2) {
  int i = blockIdx.x * 256 + threadIdx.x;
  if (i < NBATCH * NT) {
    float x = __fadd_rn(__fmul_rn(f0n[i], C1), C2);
    f0hz[i] = (float)exp2((double)x);
  }
}

// ---------------- MLP heads (8 rows / block) ----------------
__global__ __launch_bounds__(256) void k_mlp(
    const float* __restrict__ z,
    const float* __restrict__ W1p, const float* __restrict__ b1p,
    const float* __restrict__ W2p, const float* __restrict__ b2p,
    const float* __restrict__ W1n, const float* __restrict__ b1n,
    const float* __restrict__ W2n, const float* __restrict__ b2n,
    float* __restrict__ amp, float* __restrict__ nmag) {
  int row0 = blockIdx.x * 8;
  int tid  = threadIdx.x;
  __shared__ float zs[8][ND];
  __shared__ float hp[8][256];
  __shared__ float hn[8][256];
  for (int i = tid; i < 8 * ND; i += 256) {
    int r = i >> 7, d = i & 127;
    zs[r][d] = z[(size_t)(row0 + r) * ND + d];
  }
  __syncthreads();
  float ap[8], an[8];
  float bp = b1p[tid], bn = b1n[tid];
#pragma unroll
  for (int r = 0; r < 8; ++r) { ap[r] = bp; an[r] = bn; }
  for (int d = 0; d < ND; ++d) {
    float w1 = W1p[d * 256 + tid];
    float w2 = W1n[d * 256 + tid];
#pragma unroll
    for (int r = 0; r < 8; ++r) {
      float zz = zs[r][d];
      ap[r] = fmaf(zz, w1, ap[r]);
      an[r] = fmaf(zz, w2, an[r]);
    }
  }
#pragma unroll
  for (int r = 0; r < 8; ++r) {
    hp[r][tid] = fmaxf(ap[r], 0.0f);
    hn[r][tid] = fmaxf(an[r], 0.0f);
  }
  __syncthreads();
  // noise-mags head (256 outputs)
  float a2[8];
  float bn2 = b2n[tid];
#pragma unroll
  for (int r = 0; r < 8; ++r) a2[r] = bn2;
  for (int h = 0; h < 256; ++h) {
    float w = W2n[h * 256 + tid];
#pragma unroll
    for (int r = 0; r < 8; ++r) a2[r] = fmaf(hn[r][h], w, a2[r]);
  }
#pragma unroll
  for (int r = 0; r < 8; ++r)
    nmag[(size_t)(row0 + r) * 256 + tid] = 1.0f / (1.0f + expf(-a2[r]));
  // amp head (64 outputs)
  if (tid < 64) {
    float a1[8];
    float bp2 = b2p[tid];
#pragma unroll
    for (int r = 0; r < 8; ++r) a1[r] = bp2;
    for (int h = 0; h < 256; ++h) {
      float w = W2p[h * 64 + tid];
#pragma unroll
      for (int r = 0; r < 8; ++r) a1[r] = fmaf(hp[r][h], w, a1[r]);
    }
#pragma unroll
    for (int r = 0; r < 8; ++r)
      amp[(size_t)(row0 + r) * 64 + tid] = 1.0f / (1.0f + expf(-a1[r]));
  }
}

// ---------------- mean over frames (== mean of lin_interp, exact) ----------------
__global__ __launch_bounds__(256) void k_mean(const float* __restrict__ nmag,
                                              float* __restrict__ mm) {
  int b = blockIdx.x, k = threadIdx.x;
  float s = 0.0f;
  for (int t = 0; t < NT; ++t) s += nmag[((size_t)b * NT + t) * 256 + k];
  mm[b * 256 + k] = s * (1.0f / 500.0f);
}

// ---------------- basis G[n][i] = sum_k hat_i(k) * cos(2 pi n k / 88000) ----------------
__global__ __launch_bounds__(256) void k_basis(float* __restrict__ G) {
  int n = blockIdx.x;       // 0..1024
  int i = threadIdx.x;      // bin 0..255
  int start = 1, end = 43999;
  if (i > 0) {
    int s0 = (int)(((float)i - 0.5f) * 171.87890625f - 0.5f) - 4;
    if (s0 > start) start = s0;
  }
  int e0 = (int)(((float)i + 1.5f) * 171.87890625f - 0.5f) + 4;
  if (e0 < end) end = e0;
  float acc = 0.0f;
  int m = (n * start) % TAUD;
  for (int k = start; k <= end; ++k) {
    float kf  = (float)k;
    float src = __fsub_rn(__fmul_rn(__fadd_rn(kf, 0.5f), SCALE_NF), 0.5f);
    src = fminf(fmaxf(src, 0.0f), 255.0f);
    int i0 = (int)src;
    float w = __fsub_rn(src, (float)i0);
    float wt = 0.0f;
    if (i0 == i) wt = __fsub_rn(1.0f, w);
    int i1 = (i0 < 255) ? i0 + 1 : 255;
    if (i1 == i) wt = __fadd_rn(wt, w);
    acc = fmaf(wt, __cosf((float)m * CANG), acc);
    m += n; if (m >= TAUD) m -= TAUD;
  }
  G[n * 256 + i] = acc;
}

// ---------------- combine: h[b][n] = (F0 +- FN + 2*sum_i mm_i G[n][i]) / N ----------------
__global__ __launch_bounds__(256) void k_hc(const float* __restrict__ mm,
                                            const float* __restrict__ G,
                                            float* __restrict__ hh) {
  int n = blockIdx.x;       // 0..1024
  int tid = threadIdx.x;
  float g = G[n * 256 + tid];
  __shared__ float red[256];
  for (int b = 0; b < NBATCH; ++b) {
    red[tid] = mm[b * 256 + tid] * g;
    __syncthreads();
    for (int st = 128; st > 0; st >>= 1) {
      if (tid < st) red[tid] += red[tid + st];
      __syncthreads();
    }
    if (tid == 0) {
      float F0 = mm[b * 256 + 0];
      float src = __fsub_rn(__fmul_rn(__fadd_rn(44000.0f, 0.5f), SCALE_NF), 0.5f);
      src = fminf(fmaxf(src, 0.0f), 255.0f);
      int i0 = (int)src;
      float w = __fsub_rn(src, (float)i0);
      int i1 = (i0 < 255) ? i0 + 1 : 255;
      float FN = __fadd_rn(__fmul_rn(mm[b * 256 + i0], __fsub_rn(1.0f, w)),
                           __fmul_rn(mm[b * 256 + i1], w));
      float tot = 2.0f * red[0] + F0 + ((n & 1) ? -FN : FN);
      hh[b * (LCONV + 1) + n] = tot * (1.0f / 88000.0f);
    }
    __syncthreads();
  }
}

// ---------------- cumsum top levels: Brent-Kung (associative_scan DAG) ----------------
__global__ __launch_bounds__(256) void k_scan_top(const float* __restrict__ f0hz,
                                                  float* __restrict__ pref4) {
  int bp = blockIdx.x;
  int b = bp >> 6, p = bp & 63;
  float pf = (float)(p + 1);
  __shared__ float sf0[NT];
  __shared__ float lev[10992];
  int tid = threadIdx.x;
  for (int i = tid; i < NT; i += 256) sf0[i] = f0hz[b * NT + i];
  __syncthreads();
  for (int m = tid; m < 5500; m += 256) {
    float v[16];
#pragma unroll
    for (int t = 0; t < 16; ++t) v[t] = inc_val(sf0, m * 16 + t, pf);
    float s1[8];
#pragma unroll
    for (int t = 0; t < 8; ++t) s1[t] = __fadd_rn(v[2 * t], v[2 * t + 1]);
    float s2[4];
#pragma unroll
    for (int t = 0; t < 4; ++t) s2[t] = __fadd_rn(s1[2 * t], s1[2 * t + 1]);
    float s3a = __fadd_rn(s2[0], s2[1]);
    float s3b = __fadd_rn(s2[2], s2[3]);
    lev[m] = __fadd_rn(s3a, s3b);
  }
  __syncthreads();
  const int sizes[13] = {5500, 2750, 1375, 687, 343, 171, 85, 42, 21, 10, 5, 2, 1};
  const int offs[13]  = {0, 5500, 8250, 9625, 10312, 10655, 10826, 10911,
                         10953, 10974, 10984, 10989, 10991};
  for (int L = 1; L < 13; ++L) {
    int n = sizes[L];
    const float* src = lev + offs[L - 1];
    float* dst = lev + offs[L];
    for (int k2 = tid; k2 < n; k2 += 256)
      dst[k2] = __fadd_rn(src[2 * k2], src[2 * k2 + 1]);
    __syncthreads();
  }
  for (int L = 11; L >= 0; --L) {
    int n = sizes[L];
    float* cur = lev + offs[L];
    const float* up = lev + offs[L + 1];
    for (int idx = 1 + tid; idx < n; idx += 256) {
      float val;
      if (idx & 1) val = up[(idx - 1) >> 1];
      else         val = __fadd_rn(up[(idx >> 1) - 1], cur[idx]);
      cur[idx] = val;
    }
    __syncthreads();
  }
  for (int m = tid; m < 5500; m += 256)
    pref4[(size_t)bp * 5500 + m] = lev[m];
}

// ---------------- fused harmonic synth ----------------
__global__ __launch_bounds__(256) void k_harm(const float* __restrict__ f0hz,
                                              const float* __restrict__ amp,
                                              const float* __restrict__ pref4,
                                              float* __restrict__ hpart) {
  int chunk = blockIdx.x, b = blockIdx.y, g = blockIdx.z;
  int tid = threadIdx.x;
  int m = chunk * 256 + tid;
  bool act = (m < 5500);
  __shared__ float sf0[NT];
  for (int i = tid; i < NT; i += 256) sf0[i] = f0hz[b * NT + i];
  __syncthreads();
  int mm_ = act ? m : 0;
  int j0 = mm_ * 16;
  float wv[16];
  unsigned damask = 0, dnmask = 0;
  int f = 0;
#pragma unroll
  for (int t = 0; t < 16; ++t) {
    int j = j0 + t;
    float jf = (float)j;
    float src = __fsub_rn(__fmul_rn(__fadd_rn(jf, 0.5f), SCALE_TA), 0.5f);
    src = fminf(fmaxf(src, 0.0f), 499.0f);
    int a = (int)src;
    if (t == 0) f = a;                 // i0 monotone nondecreasing in j
    wv[t] = __fsub_rn(src, (float)a);
    damask |= (unsigned)(a - f) << t;  // in {0,1}
    int ni = (int)__fmul_rn(jf, SCALE_TA);
    ni = ni > 499 ? 499 : ni;
    dnmask |= (unsigned)(ni - f) << t; // in {0,1}
  }
  int f1 = (f + 1 > 499) ? 499 : f + 1;
  int f2 = (f + 2 > 499) ? 499 : f + 2;
  float s0 = sf0[f], s1 = sf0[f1], s2 = sf0[f2];

  float acc[16];
#pragma unroll
  for (int t = 0; t < 16; ++t) acc[t] = 0.0f;

  for (int pp = 0; pp < 16; ++pp) {
    int p = g * 16 + pp;
    float pf = (float)(p + 1);
    float fs0 = __fmul_rn(s0, pf);
    float fs1 = __fmul_rn(s1, pf);
    if (!(fs0 < 22050.0f) && !(fs1 < 22050.0f)) break;
    float fs2 = __fmul_rn(s2, pf);
    size_t pbase = ((size_t)(b * NPART + p)) * 5500;
    float left = (mm_ > 0) ? pref4[pbase + mm_ - 1] : 0.0f;
    float P4 = pref4[pbase + mm_];
    float v[16];
#pragma unroll
    for (int t = 0; t < 16; ++t) {
      bool d = (damask >> t) & 1;
      float fa = d ? fs1 : fs0;
      float fb = d ? fs2 : fs1;
      float w = wv[t];
      float fu = __fadd_rn(__fmul_rn(fa, __fsub_rn(1.0f, w)), __fmul_rn(fb, w));
      v[t] = __fdiv_rn(fu, 44100.0f);
    }
    float s1t[8];
#pragma unroll
    for (int t = 0; t < 8; ++t) s1t[t] = __fadd_rn(v[2 * t], v[2 * t + 1]);
    float s2t[4];
#pragma unroll
    for (int t = 0; t < 4; ++t) s2t[t] = __fadd_rn(s1t[2 * t], s1t[2 * t + 1]);
    float s3_0 = __fadd_rn(s2t[0], s2t[1]);
    bool fz = (mm_ == 0);
    float l3_0 = fz ? s3_0 : __fadd_rn(left, s3_0);
    float l2_0 = fz ? s2t[0] : __fadd_rn(left, s2t[0]);
    float l2_1 = l3_0;
    float l2_2 = __fadd_rn(l3_0, s2t[2]);
    float l2_3 = P4;
    float l1_0 = fz ? s1t[0] : __fadd_rn(left, s1t[0]);
    float l1_1 = l2_0;
    float l1_2 = __fadd_rn(l2_0, s1t[2]);
    float l1_3 = l2_1;
    float l1_4 = __fadd_rn(l2_1, s1t[4]);
    float l1_5 = l2_2;
    float l1_6 = __fadd_rn(l2_2, s1t[6]);
    float l1_7 = l2_3;
    float ph[16];
    ph[0]  = fz ? v[0] : __fadd_rn(left, v[0]);
    ph[1]  = l1_0;
    ph[2]  = __fadd_rn(l1_0, v[2]);
    ph[3]  = l1_1;
    ph[4]  = __fadd_rn(l1_1, v[4]);
    ph[5]  = l1_2;
    ph[6]  = __fadd_rn(l1_2, v[6]);
    ph[7]  = l1_3;
    ph[8]  = __fadd_rn(l1_3, v[8]);
    ph[9]  = l1_4;
    ph[10] = __fadd_rn(l1_4, v[10]);
    ph[11] = l1_5;
    ph[12] = __fadd_rn(l1_5, v[12]);
    ph[13] = l1_6;
    ph[14] = __fadd_rn(l1_6, v[14]);
    ph[15] = l1_7;
    float ga0 = amp[((size_t)(b * NT + f)) * 64 + p];
    float ga1 = amp[((size_t)(b * NT + f1)) * 64 + p];
    float ga2 = amp[((size_t)(b * NT + f2)) * 64 + p];
#pragma unroll
    for (int t = 0; t < 16; ++t) {
      bool dn = (dnmask >> t) & 1;
      float fr = dn ? fs1 : fs0;
      if (fr < 22050.0f) {
        float x = __fmul_rn(ph[t], TWOPI_F);
        float s = sin_ref(x);
        bool d = (damask >> t) & 1;
        float lo = d ? ga1 : ga0;
        float hi = d ? ga2 : ga1;
        float w = wv[t];
        float au = __fadd_rn(__fmul_rn(lo, __fsub_rn(1.0f, w)), __fmul_rn(hi, w));
        acc[t] = __fadd_rn(acc[t], __fmul_rn(s, au));
      }
    }
  }
  if (act) {
    size_t obase = ((size_t)g * NBATCH + b) * TAUD + (size_t)j0;
#pragma unroll
    for (int t = 0; t < 16; ++t) hpart[obase + t] = acc[t];
  }
}

// ---------------- circular convolution (truncated +-LCONV) ----------------
// SoA 4-plane LDS: plane[c][k] = xs[4k+c] (xs index = t - t0 + 1024), plane
// stride 776 (8 mod 32 -> staggered banks). Each read: one dword, stride-1
// lane addressing -> conflict-free regardless of codegen. 8 taps x 4 outputs
// per group; ascending-d fmaf(h, xm+xp, acc) per output -> bit-exact.
#define PSTR 776
__global__ __launch_bounds__(256) void k_conv(const float* __restrict__ noise,
                                              const float* __restrict__ hh,
                                              float* __restrict__ ynz) {
  int b = blockIdx.y;
  int t0 = blockIdx.x * 1024;
  int tid = threadIdx.x;
  __shared__ float xsp[4 * PSTR];     // 4 planes of 768 (+8 pad)
  __shared__ float hsh[LCONV];        // h[1..1024]
  const float* hb = hh + b * (LCONV + 1);
  for (int i = tid; i < 3072; i += 256) {
    int j = t0 - 1024 + i;
    if (j < 0) j += TAUD;
    else if (j >= TAUD) j -= TAUD;
    xsp[(i & 3) * PSTR + (i >> 2)] = noise[(size_t)b * TAUD + j];
  }
  for (int i = tid; i < LCONV; i += 256) hsh[i] = hb[1 + i];
  __syncthreads();
  float h0 = hb[0];
  int B4 = tid + 256;                 // plane index of x[t0 + 4*tid]
  float a0 = h0 * xsp[0 * PSTR + B4];
  float a1 = h0 * xsp[1 * PSTR + B4];
  float a2 = h0 * xsp[2 * PSTR + B4];
  float a3 = h0 * xsp[3 * PSTR + B4];
  for (int g = 0; g < 128; ++g) {     // taps d = 8g+1 .. 8g+8
    int km = tid + 254 - 2 * g;       // minus side base (plane k)
    int kp = tid + 256 + 2 * g;       // plus side base
    // mv[u] = xs[B-8g-8+u] u=0..10 ; pv[u] = xs[B+8g+u] u=1..11
    float mv0 = xsp[0 * PSTR + km],     mv1 = xsp[1 * PSTR + km];
    float mv2 = xsp[2 * PSTR + km],     mv3 = xsp[3 * PSTR + km];
    float mv4 = xsp[0 * PSTR + km + 1], mv5 = xsp[1 * PSTR + km + 1];
    float mv6 = xsp[2 * PSTR + km + 1], mv7 = xsp[3 * PSTR + km + 1];
    float mv8 = xsp[0 * PSTR + km + 2], mv9 = xsp[1 * PSTR + km + 2];
    float mv10 = xsp[2 * PSTR + km + 2];
    float pv1 = xsp[1 * PSTR + kp],     pv2 = xsp[2 * PSTR + kp];
    float pv3 = xsp[3 * PSTR + kp];
    float pv4 = xsp[0 * PSTR + kp + 1], pv5 = xsp[1 * PSTR + kp + 1];
    float pv6 = xsp[2 * PSTR + kp + 1], pv7 = xsp[3 * PSTR + kp + 1];
    float pv8 = xsp[0 * PSTR + kp + 2], pv9 = xsp[1 * PSTR + kp + 2];
    float pv10 = xsp[2 * PSTR + kp + 2], pv11 = xsp[3 * PSTR + kp + 2];
    int hbase = 8 * g;                // uniform -> broadcast reads
    float hv0 = hsh[hbase + 0], hv1 = hsh[hbase + 1];
    float hv2 = hsh[hbase + 2], hv3 = hsh[hbase + 3];
    float hv4 = hsh[hbase + 4], hv5 = hsh[hbase + 5];
    float hv6 = hsh[hbase + 6], hv7 = hsh[hbase + 7];
    // out k, tap d=8g+1+dd: xm = mv[k+7-dd], xp = pv[k+1+dd], dd ascending
    a0 = fmaf(hv0, mv7 + pv1, a0);
    a0 = fmaf(hv1, mv6 + pv2, a0);
    a0 = fmaf(hv2, mv5 + pv3, a0);
    a0 = fmaf(hv3, mv4 + pv4, a0);
    a0 = fmaf(hv4, mv3 + pv5, a0);
    a0 = fmaf(hv5, mv2 + pv6, a0);
    a0 = fmaf(hv6, mv1 + pv7, a0);
    a0 = fmaf(hv7, mv0 + pv8, a0);
    a1 = fmaf(hv0, mv8 + pv2, a1);
    a1 = fmaf(hv1, mv7 + pv3, a1);
    a1 = fmaf(hv2, mv6 + pv4, a1);
    a1 = fmaf(hv3, mv5 + pv5, a1);
    a1 = fmaf(hv4, mv4 + pv6, a1);
    a1 = fmaf(hv5, mv3 + pv7, a1);
    a1 = fmaf(hv6, mv2 + pv8, a1);
    a1 = fmaf(hv7, mv1 + pv9, a1);
    a2 = fmaf(hv0, mv9 + pv3, a2);
    a2 = fmaf(hv1, mv8 + pv4, a2);
    a2 = fmaf(hv2, mv7 + pv5, a2);
    a2 = fmaf(hv3, mv6 + pv6, a2);
    a2 = fmaf(hv4, mv5 + pv7, a2);
    a2 = fmaf(hv5, mv4 + pv8, a2);
    a2 = fmaf(hv6, mv3 + pv9, a2);
    a2 = fmaf(hv7, mv2 + pv10, a2);
    a3 = fmaf(hv0, mv10 + pv4, a3);
    a3 = fmaf(hv1, mv9 + pv5, a3);
    a3 = fmaf(hv2, mv8 + pv6, a3);
    a3 = fmaf(hv3, mv7 + pv7, a3);
    a3 = fmaf(hv4, mv6 + pv8, a3);
    a3 = fmaf(hv5, mv5 + pv9, a3);
    a3 = fmaf(hv6, mv4 + pv10, a3);
    a3 = fmaf(hv7, mv3 + pv11, a3);
  }
  int t = t0 + tid * 4;
  if (t < TAUD) {                     // TAUD%4==0 -> all 4 valid together
    float4 o = make_float4(a0 * 0.1f, a1 * 0.1f, a2 * 0.1f, a3 * 0.1f);
    *reinterpret_cast<float4*>(&ynz[(size_t)b * TAUD + t]) = o;
  }
}

// ---------------- final mix ----------------
__global__ __launch_bounds__(256) void k_final(const float* __restrict__ hpart,
                                               const float* __restrict__ ynz,
                                               const float* __restrict__ loud,
                                               float* __restrict__ out) {
  int idx = blockIdx.x * 256 + threadIdx.x;
  if (idx >= NBATCH * TAUD) return;
  int b = idx / TAUD, j = idx - b * TAUD;
  int i0, i1; float w;
  iparams(j, i0, i1, w);
  float env = __fadd_rn(__fmul_rn(loud[b * NT + i0], __fsub_rn(1.0f, w)),
                        __fmul_rn(loud[b * NT + i1], w));
  const size_t S = (size_t)NBATCH * TAUD;
  float hsum = __fadd_rn(__fadd_rn(__fadd_rn(hpart[idx], hpart[S + idx]),
                                   hpart[2 * S + idx]),
                         hpart[3 * S + idx]);
  out[idx] = __fmul_rn(__fadd_rn(hsum, ynz[idx]), env);
}

}  // namespace

extern "C" void kernel_launch(void* const* d_in, const int* in_sizes, int n_in,
                              void* d_out, int out_size, void* d_ws, size_t ws_size,
                              hipStream_t stream) {
  const float* z    = (const float*)d_in[0];
  const float* f0n  = (const float*)d_in[1];
  const float* loud = (const float*)d_in[2];
  const float* nz   = (const float*)d_in[3];
  const float* W1p  = (const float*)d_in[4];
  const float* b1p  = (const float*)d_in[5];
  const float* W2p  = (const float*)d_in[6];
  const float* b2p  = (const float*)d_in[7];
  const float* W1n  = (const float*)d_in[8];
  const float* b1n  = (const float*)d_in[9];
  const float* W2n  = (const float*)d_in[10];
  const float* b2n  = (const float*)d_in[11];
  float* out = (float*)d_out;
  float* ws  = (float*)d_ws;

  size_t off = 0;
  float* amp   = ws + off; off += (size_t)NBATCH * NT * NPART;      // 256,000
  float* nmag  = ws + off; off += (size_t)NBATCH * NT * NBINS;      // 1,024,000
  float* f0hz  = ws + off; off += (size_t)NBATCH * NT;              // 4,000
  float* mmw   = ws + off; off += (size_t)NBATCH * NBINS;           // 2,048
  float* G     = ws + off; off += (size_t)(LCONV + 1) * NBINS;      // 262,400
  float* hh    = ws + off; off += (size_t)NBATCH * (LCONV + 1);     // 8,200
  float* ynz   = ws + off; off += (size_t)NBATCH * TAUD;            // 704,000
  float* pref4 = ws + off; off += (size_t)NBATCH * NPART * 5500;    // 2,816,000
  float* hpart = ws + off; off += (size_t)4 * NBATCH * TAUD;        // 2,816,000
  (void)ws_size; (void)in_sizes; (void)n_in; (void)out_size;        // ~31.2 MB total

  double HI = log2(2093.0), LO = log2(32.7);
  float C1 = (float)(HI - LO), C2 = (float)LO;

  k_basis<<<LCONV + 1, 256, 0, stream>>>(G);
  k_f0<<<(NBATCH * NT + 255) / 256, 256, 0, stream>>>(f0n, f0hz, C1, C2);
  k_mlp<<<(NBATCH * NT) / 8, 256, 0, stream>>>(z, W1p, b1p, W2p, b2p,
                                               W1n, b1n, W2n, b2n, amp, nmag);
  k_mean<<<NBATCH, 256, 0, stream>>>(nmag, mmw);
  k_hc<<<LCONV + 1, 256, 0, stream>>>(mmw, G, hh);
  k_scan_top<<<NBATCH * NPART, 256, 0, stream>>>(f0hz, pref4);
  dim3 gh(22, NBATCH, 4);
  k_harm<<<gh, 256, 0, stream>>>(f0hz, amp, pref4, hpart);
  dim3 gc((TAUD + 1023) / 1024, NBATCH);
  k_conv<<<gc, 256, 0, stream>>>(nz, hh, ynz);
  k_final<<<(NBATCH * TAUD + 255) / 256, 256, 0, stream>>>(hpart, ynz, loud, out);
}

// Round 6
// 295.484 us; speedup vs baseline: 1.5757x; 1.1264x over previous
//
#include <hip/hip_runtime.h>
#include <cmath>

// DDSP decoder, bit-exact-phase implementation.
// R6: (1) Markstein fma-division by 44100 (correctly rounded -> phases
//     bit-identical) in scan+harm; (2) float Cody-Waite sin reduction +
//     __sinf (v_sin) replacing double-reduce+libm (sin-only, ~5e-4 absmax
//     budget); (3) k_conv 8 outputs/thread, float2 plane reads, h via
//     uniform global loads (s_load) -- conv chain order unchanged.

#define NBATCH 8
#define NT     500
#define ND     128
#define TAUD   88000
#define NPART  64
#define NBINS  256
#define NFREQ  44001
#define LCONV  1024

namespace {

constexpr float  SCALE_TA = (float)(500.0 / 88000.0);   // lin_interp scale, fp32 like jnp
constexpr float  SCALE_NF = (float)(256.0 / 44001.0);
constexpr float  TWOPI_F  = (float)6.283185307179586476925286766559;
constexpr float  CANG     = (float)(6.283185307179586476925286766559 / 88000.0);
constexpr float  INV_SR   = 1.0f / 44100.0f;            // RN reciprocal
constexpr float  INV2PI_F = 0.15915494309189535f;       // RN(1/2pi)
constexpr float  PI2_HI   = 6.2831854820251464844f;     // RN(2pi) fp32
constexpr float  PI2_LO   = -1.7484556000744487e-7f;    // RN(2pi - PI2_HI)

__device__ __forceinline__ void iparams(int j, int& i0, int& i1, float& w) {
  float jf  = (float)j;
  float src = __fsub_rn(__fmul_rn(__fadd_rn(jf, 0.5f), SCALE_TA), 0.5f);
  src = fminf(fmaxf(src, 0.0f), 499.0f);
  int a = (int)src;            // floor (src >= 0)
  i0 = a;
  i1 = (a + 1 > 499) ? 499 : (a + 1);
  w  = __fsub_rn(src, (float)a);
}

// correctly-rounded x/44100 (Markstein: RN recip + 2 fma) == __fdiv_rn
__device__ __forceinline__ float div_sr(float x) {
  float q0 = __fmul_rn(x, INV_SR);
  float e  = __builtin_fmaf(-44100.0f, q0, x);
  return __builtin_fmaf(e, INV_SR, q0);
}

__device__ __forceinline__ float inc_val(const float* sf0, int j, float pf) {
  int i0, i1; float w;
  iparams(j, i0, i1, w);
  float fa = __fmul_rn(sf0[i0], pf);
  float fb = __fmul_rn(sf0[i1], pf);
  float fu = __fadd_rn(__fmul_rn(fa, __fsub_rn(1.0f, w)), __fmul_rn(fb, w));
  return div_sr(fu);
}

// sin of the fp32 value x (|x| up to ~3e5): float Cody-Waite reduce + v_sin.
// |err vs libm sinf(x)| <= ~1e-6 (reduce 3e-7 + hw sin ~1e-6).
__device__ __forceinline__ float sin_fast(float x) {
  float k = rintf(__fmul_rn(x, INV2PI_F));
  float r = __builtin_fmaf(-k, PI2_HI, x);
  r = __builtin_fmaf(-k, PI2_LO, r);
  return __sinf(r);
}

// ---------------- f0 (Hz) ----------------
__global__ __launch_bounds__(256) void k_f0(const float* __restrict__ f0n,
                                            float* __restrict__ f0hz,
                                            float C1, float C2) {
  int i = blockIdx.x * 256 + threadIdx.x;
  if (i < NBATCH * NT) {
    float x = __fadd_rn(__fmul_rn(f0n[i], C1), C2);
    f0hz[i] = (float)exp2((double)x);
  }
}

// ---------------- MLP heads (8 rows / block) ----------------
__global__ __launch_bounds__(256) void k_mlp(
    const float* __restrict__ z,
    const float* __restrict__ W1p, const float* __restrict__ b1p,
    const float* __restrict__ W2p, const float* __restrict__ b2p,
    const float* __restrict__ W1n, const float* __restrict__ b1n,
    const float* __restrict__ W2n, const float* __restrict__ b2n,
    float* __restrict__ amp, float* __restrict__ nmag) {
  int row0 = blockIdx.x * 8;
  int tid  = threadIdx.x;
  __shared__ float zs[8][ND];
  __shared__ float hp[8][256];
  __shared__ float hn[8][256];
  for (int i = tid; i < 8 * ND; i += 256) {
    int r = i >> 7, d = i & 127;
    zs[r][d] = z[(size_t)(row0 + r) * ND + d];
  }
  __syncthreads();
  float ap[8], an[8];
  float bp = b1p[tid], bn = b1n[tid];
#pragma unroll
  for (int r = 0; r < 8; ++r) { ap[r] = bp; an[r] = bn; }
  for (int d = 0; d < ND; ++d) {
    float w1 = W1p[d * 256 + tid];
    float w2 = W1n[d * 256 + tid];
#pragma unroll
    for (int r = 0; r < 8; ++r) {
      float zz = zs[r][d];
      ap[r] = fmaf(zz, w1, ap[r]);
      an[r] = fmaf(zz, w2, an[r]);
    }
  }
#pragma unroll
  for (int r = 0; r < 8; ++r) {
    hp[r][tid] = fmaxf(ap[r], 0.0f);
    hn[r][tid] = fmaxf(an[r], 0.0f);
  }
  __syncthreads();
  float a2[8];
  float bn2 = b2n[tid];
#pragma unroll
  for (int r = 0; r < 8; ++r) a2[r] = bn2;
  for (int h = 0; h < 256; ++h) {
    float w = W2n[h * 256 + tid];
#pragma unroll
    for (int r = 0; r < 8; ++r) a2[r] = fmaf(hn[r][h], w, a2[r]);
  }
#pragma unroll
  for (int r = 0; r < 8; ++r)
    nmag[(size_t)(row0 + r) * 256 + tid] = 1.0f / (1.0f + expf(-a2[r]));
  if (tid < 64) {
    float a1[8];
    float bp2 = b2p[tid];
#pragma unroll
    for (int r = 0; r < 8; ++r) a1[r] = bp2;
    for (int h = 0; h < 256; ++h) {
      float w = W2p[h * 64 + tid];
#pragma unroll
      for (int r = 0; r < 8; ++r) a1[r] = fmaf(hp[r][h], w, a1[r]);
    }
#pragma unroll
    for (int r = 0; r < 8; ++r)
      amp[(size_t)(row0 + r) * 64 + tid] = 1.0f / (1.0f + expf(-a1[r]));
  }
}

// ---------------- mean over frames (== mean of lin_interp, exact) ----------------
__global__ __launch_bounds__(256) void k_mean(const float* __restrict__ nmag,
                                              float* __restrict__ mm) {
  int b = blockIdx.x, k = threadIdx.x;
  float s = 0.0f;
  for (int t = 0; t < NT; ++t) s += nmag[((size_t)b * NT + t) * 256 + k];
  mm[b * 256 + k] = s * (1.0f / 500.0f);
}

// ---------------- basis G[n][i] = sum_k hat_i(k) * cos(2 pi n k / 88000) ----------------
__global__ __launch_bounds__(256) void k_basis(float* __restrict__ G) {
  int n = blockIdx.x;       // 0..1024
  int i = threadIdx.x;      // bin 0..255
  int start = 1, end = 43999;
  if (i > 0) {
    int s0 = (int)(((float)i - 0.5f) * 171.87890625f - 0.5f) - 4;
    if (s0 > start) start = s0;
  }
  int e0 = (int)(((float)i + 1.5f) * 171.87890625f - 0.5f) + 4;
  if (e0 < end) end = e0;
  float acc = 0.0f;
  int m = (n * start) % TAUD;
  for (int k = start; k <= end; ++k) {
    float kf  = (float)k;
    float src = __fsub_rn(__fmul_rn(__fadd_rn(kf, 0.5f), SCALE_NF), 0.5f);
    src = fminf(fmaxf(src, 0.0f), 255.0f);
    int i0 = (int)src;
    float w = __fsub_rn(src, (float)i0);
    float wt = 0.0f;
    if (i0 == i) wt = __fsub_rn(1.0f, w);
    int i1 = (i0 < 255) ? i0 + 1 : 255;
    if (i1 == i) wt = __fadd_rn(wt, w);
    acc = fmaf(wt, __cosf((float)m * CANG), acc);
    m += n; if (m >= TAUD) m -= TAUD;
  }
  G[n * 256 + i] = acc;
}

// ---------------- combine: h[b][n] = (F0 +- FN + 2*sum_i mm_i G[n][i]) / N ----------------
__global__ __launch_bounds__(256) void k_hc(const float* __restrict__ mm,
                                            const float* __restrict__ G,
                                            float* __restrict__ hh) {
  int n = blockIdx.x;       // 0..1024
  int tid = threadIdx.x;
  float g = G[n * 256 + tid];
  __shared__ float red[256];
  for (int b = 0; b < NBATCH; ++b) {
    red[tid] = mm[b * 256 + tid] * g;
    __syncthreads();
    for (int st = 128; st > 0; st >>= 1) {
      if (tid < st) red[tid] += red[tid + st];
      __syncthreads();
    }
    if (tid == 0) {
      float F0 = mm[b * 256 + 0];
      float src = __fsub_rn(__fmul_rn(__fadd_rn(44000.0f, 0.5f), SCALE_NF), 0.5f);
      src = fminf(fmaxf(src, 0.0f), 255.0f);
      int i0 = (int)src;
      float w = __fsub_rn(src, (float)i0);
      int i1 = (i0 < 255) ? i0 + 1 : 255;
      float FN = __fadd_rn(__fmul_rn(mm[b * 256 + i0], __fsub_rn(1.0f, w)),
                           __fmul_rn(mm[b * 256 + i1], w));
      float tot = 2.0f * red[0] + F0 + ((n & 1) ? -FN : FN);
      hh[b * (LCONV + 1) + n] = tot * (1.0f / 88000.0f);
    }
    __syncthreads();
  }
}

// ---------------- cumsum top levels: Brent-Kung (associative_scan DAG) ----------------
__global__ __launch_bounds__(256) void k_scan_top(const float* __restrict__ f0hz,
                                                  float* __restrict__ pref4) {
  int bp = blockIdx.x;
  int b = bp >> 6, p = bp & 63;
  float pf = (float)(p + 1);
  __shared__ float sf0[NT];
  __shared__ float lev[10992];
  int tid = threadIdx.x;
  for (int i = tid; i < NT; i += 256) sf0[i] = f0hz[b * NT + i];
  __syncthreads();
  for (int m = tid; m < 5500; m += 256) {
    float v[16];
#pragma unroll
    for (int t = 0; t < 16; ++t) v[t] = inc_val(sf0, m * 16 + t, pf);
    float s1[8];
#pragma unroll
    for (int t = 0; t < 8; ++t) s1[t] = __fadd_rn(v[2 * t], v[2 * t + 1]);
    float s2[4];
#pragma unroll
    for (int t = 0; t < 4; ++t) s2[t] = __fadd_rn(s1[2 * t], s1[2 * t + 1]);
    float s3a = __fadd_rn(s2[0], s2[1]);
    float s3b = __fadd_rn(s2[2], s2[3]);
    lev[m] = __fadd_rn(s3a, s3b);
  }
  __syncthreads();
  const int sizes[13] = {5500, 2750, 1375, 687, 343, 171, 85, 42, 21, 10, 5, 2, 1};
  const int offs[13]  = {0, 5500, 8250, 9625, 10312, 10655, 10826, 10911,
                         10953, 10974, 10984, 10989, 10991};
  for (int L = 1; L < 13; ++L) {
    int n = sizes[L];
    const float* src = lev + offs[L - 1];
    float* dst = lev + offs[L];
    for (int k2 = tid; k2 < n; k2 += 256)
      dst[k2] = __fadd_rn(src[2 * k2], src[2 * k2 + 1]);
    __syncthreads();
  }
  for (int L = 11; L >= 0; --L) {
    int n = sizes[L];
    float* cur = lev + offs[L];
    const float* up = lev + offs[L + 1];
    for (int idx = 1 + tid; idx < n; idx += 256) {
      float val;
      if (idx & 1) val = up[(idx - 1) >> 1];
      else         val = __fadd_rn(up[(idx >> 1) - 1], cur[idx]);
      cur[idx] = val;
    }
    __syncthreads();
  }
  for (int m = tid; m < 5500; m += 256)
    pref4[(size_t)bp * 5500 + m] = lev[m];
}

// ---------------- fused harmonic synth ----------------
__global__ __launch_bounds__(256) void k_harm(const float* __restrict__ f0hz,
                                              const float* __restrict__ amp,
                                              const float* __restrict__ pref4,
                                              float* __restrict__ hpart) {
  int chunk = blockIdx.x, b = blockIdx.y, g = blockIdx.z;
  int tid = threadIdx.x;
  int m = chunk * 256 + tid;
  bool act = (m < 5500);
  __shared__ float sf0[NT];
  for (int i = tid; i < NT; i += 256) sf0[i] = f0hz[b * NT + i];
  __syncthreads();
  int mm_ = act ? m : 0;
  int j0 = mm_ * 16;
  float wv[16], wm[16];
  unsigned damask = 0, dnmask = 0;
  int f = 0;
#pragma unroll
  for (int t = 0; t < 16; ++t) {
    int j = j0 + t;
    float jf = (float)j;
    float src = __fsub_rn(__fmul_rn(__fadd_rn(jf, 0.5f), SCALE_TA), 0.5f);
    src = fminf(fmaxf(src, 0.0f), 499.0f);
    int a = (int)src;
    if (t == 0) f = a;                 // i0 monotone nondecreasing in j
    wv[t] = __fsub_rn(src, (float)a);
    wm[t] = __fsub_rn(1.0f, wv[t]);
    damask |= (unsigned)(a - f) << t;  // in {0,1}
    int ni = (int)__fmul_rn(jf, SCALE_TA);
    ni = ni > 499 ? 499 : ni;
    dnmask |= (unsigned)(ni - f) << t; // in {0,1}
  }
  int f1 = (f + 1 > 499) ? 499 : f + 1;
  int f2 = (f + 2 > 499) ? 499 : f + 2;
  float s0 = sf0[f], s1 = sf0[f1], s2 = sf0[f2];

  float acc[16];
#pragma unroll
  for (int t = 0; t < 16; ++t) acc[t] = 0.0f;

  for (int pp = 0; pp < 16; ++pp) {
    int p = g * 16 + pp;
    float pf = (float)(p + 1);
    float fs0 = __fmul_rn(s0, pf);
    float fs1 = __fmul_rn(s1, pf);
    if (!(fs0 < 22050.0f) && !(fs1 < 22050.0f)) break;
    float fs2 = __fmul_rn(s2, pf);
    size_t pbase = ((size_t)(b * NPART + p)) * 5500;
    float left = (mm_ > 0) ? pref4[pbase + mm_ - 1] : 0.0f;
    float P4 = pref4[pbase + mm_];
    float v[16];
#pragma unroll
    for (int t = 0; t < 16; ++t) {
      bool d = (damask >> t) & 1;
      float fa = d ? fs1 : fs0;
      float fb = d ? fs2 : fs1;
      float fu = __fadd_rn(__fmul_rn(fa, wm[t]), __fmul_rn(fb, wv[t]));
      v[t] = div_sr(fu);
    }
    float s1t[8];
#pragma unroll
    for (int t = 0; t < 8; ++t) s1t[t] = __fadd_rn(v[2 * t], v[2 * t + 1]);
    float s2t[4];
#pragma unroll
    for (int t = 0; t < 4; ++t) s2t[t] = __fadd_rn(s1t[2 * t], s1t[2 * t + 1]);
    float s3_0 = __fadd_rn(s2t[0], s2t[1]);
    bool fz = (mm_ == 0);
    float l3_0 = fz ? s3_0 : __fadd_rn(left, s3_0);
    float l2_0 = fz ? s2t[0] : __fadd_rn(left, s2t[0]);
    float l2_1 = l3_0;
    float l2_2 = __fadd_rn(l3_0, s2t[2]);
    float l2_3 = P4;
    float l1_0 = fz ? s1t[0] : __fadd_rn(left, s1t[0]);
    float l1_1 = l2_0;
    float l1_2 = __fadd_rn(l2_0, s1t[2]);
    float l1_3 = l2_1;
    float l1_4 = __fadd_rn(l2_1, s1t[4]);
    float l1_5 = l2_2;
    float l1_6 = __fadd_rn(l2_2, s1t[6]);
    float l1_7 = l2_3;
    float ph[16];
    ph[0]  = fz ? v[0] : __fadd_rn(left, v[0]);
    ph[1]  = l1_0;
    ph[2]  = __fadd_rn(l1_0, v[2]);
    ph[3]  = l1_1;
    ph[4]  = __fadd_rn(l1_1, v[4]);
    ph[5]  = l1_2;
    ph[6]  = __fadd_rn(l1_2, v[6]);
    ph[7]  = l1_3;
    ph[8]  = __fadd_rn(l1_3, v[8]);
    ph[9]  = l1_4;
    ph[10] = __fadd_rn(l1_4, v[10]);
    ph[11] = l1_5;
    ph[12] = __fadd_rn(l1_5, v[12]);
    ph[13] = l1_6;
    ph[14] = __fadd_rn(l1_6, v[14]);
    ph[15] = l1_7;
    float ga0 = amp[((size_t)(b * NT + f)) * 64 + p];
    float ga1 = amp[((size_t)(b * NT + f1)) * 64 + p];
    float ga2 = amp[((size_t)(b * NT + f2)) * 64 + p];
#pragma unroll
    for (int t = 0; t < 16; ++t) {
      bool dn = (dnmask >> t) & 1;
      float fr = dn ? fs1 : fs0;
      if (fr < 22050.0f) {
        float x = __fmul_rn(ph[t], TWOPI_F);
        float s = sin_fast(x);
        bool d = (damask >> t) & 1;
        float lo = d ? ga1 : ga0;
        float hi = d ? ga2 : ga1;
        float au = __fadd_rn(__fmul_rn(lo, wm[t]), __fmul_rn(hi, wv[t]));
        acc[t] = __fadd_rn(acc[t], __fmul_rn(s, au));
      }
    }
  }
  if (act) {
    size_t obase = ((size_t)g * NBATCH + b) * TAUD + (size_t)j0;
#pragma unroll
    for (int t = 0; t < 16; ++t) hpart[obase + t] = acc[t];
  }
}

// ---------------- circular convolution (truncated +-LCONV) ----------------
// 8 outputs/thread (128 thr, CT=1024 tile). SoA 4-plane LDS, float2 row
// reads (8B aligned, lane stride-1 -> conflict-free); h read from GLOBAL
// with uniform index -> scalar loads, off the LDS pipe. Per-output chain:
// h0*x then ascending-d fmaf(h, xm+xp, acc) -> bit-exact vs R5.
#define CT    1024
#define PSTR2 776
__global__ __launch_bounds__(128) void k_conv(const float* __restrict__ noise,
                                              const float* __restrict__ hh,
                                              float* __restrict__ ynz) {
  int b = blockIdx.y;
  int t0 = blockIdx.x * CT;
  int tid = threadIdx.x;
  __shared__ float xsp[4 * PSTR2];    // window x[t0-1024 .. t0+CT+1024)
  for (int i = tid; i < CT + 2048; i += 128) {
    int j = t0 - 1024 + i;
    if (j < 0) j += TAUD;
    else if (j >= TAUD) j -= TAUD;
    xsp[(i & 3) * PSTR2 + (i >> 2)] = noise[(size_t)b * TAUD + j];
  }
  __syncthreads();
  const float* hb = hh + b * (LCONV + 1);
  float h0 = hb[0];
  int B = 2 * tid + 256;              // plane row of x[t0 + 8*tid]
  float a0 = h0 * xsp[0 * PSTR2 + B];
  float a1 = h0 * xsp[1 * PSTR2 + B];
  float a2 = h0 * xsp[2 * PSTR2 + B];
  float a3 = h0 * xsp[3 * PSTR2 + B];
  float a4 = h0 * xsp[0 * PSTR2 + B + 1];
  float a5 = h0 * xsp[1 * PSTR2 + B + 1];
  float a6 = h0 * xsp[2 * PSTR2 + B + 1];
  float a7 = h0 * xsp[3 * PSTR2 + B + 1];
  for (int g = 0; g < 128; ++g) {     // taps d = 8g+1 .. 8g+8
    int km = B - 2 * g - 2;           // minus rows km..km+3 (km even)
    int kp = B + 2 * g;               // plus  rows kp..kp+3 (kp even)
    float2 q0a = *(float2*)&xsp[0 * PSTR2 + km];
    float2 q1a = *(float2*)&xsp[1 * PSTR2 + km];
    float2 q2a = *(float2*)&xsp[2 * PSTR2 + km];
    float2 q3a = *(float2*)&xsp[3 * PSTR2 + km];
    float2 q0b = *(float2*)&xsp[0 * PSTR2 + km + 2];
    float2 q1b = *(float2*)&xsp[1 * PSTR2 + km + 2];
    float2 q2b = *(float2*)&xsp[2 * PSTR2 + km + 2];
    float2 q3b = *(float2*)&xsp[3 * PSTR2 + km + 2];
    float2 r0a = *(float2*)&xsp[0 * PSTR2 + kp];
    float2 r1a = *(float2*)&xsp[1 * PSTR2 + kp];
    float2 r2a = *(float2*)&xsp[2 * PSTR2 + kp];
    float2 r3a = *(float2*)&xsp[3 * PSTR2 + kp];
    float2 r0b = *(float2*)&xsp[0 * PSTR2 + kp + 2];
    float2 r1b = *(float2*)&xsp[1 * PSTR2 + kp + 2];
    float2 r2b = *(float2*)&xsp[2 * PSTR2 + kp + 2];
    float2 r3b = *(float2*)&xsp[3 * PSTR2 + kp + 2];
    // mv[u] = x[8tid-8g-8+u] u=0..14 ; pv[u] = x[8tid+8g+u] u=1..15
    float mv0 = q0a.x, mv1 = q1a.x, mv2 = q2a.x, mv3 = q3a.x;
    float mv4 = q0a.y, mv5 = q1a.y, mv6 = q2a.y, mv7 = q3a.y;
    float mv8 = q0b.x, mv9 = q1b.x, mv10 = q2b.x, mv11 = q3b.x;
    float mv12 = q0b.y, mv13 = q1b.y, mv14 = q2b.y;
    float pv1 = r1a.x, pv2 = r2a.x, pv3 = r3a.x;
    float pv4 = r0a.y, pv5 = r1a.y, pv6 = r2a.y, pv7 = r3a.y;
    float pv8 = r0b.x, pv9 = r1b.x, pv10 = r2b.x, pv11 = r3b.x;
    float pv12 = r0b.y, pv13 = r1b.y, pv14 = r2b.y, pv15 = r3b.y;
    int hb8 = 8 * g + 1;              // uniform -> s_load
    float hv0 = hb[hb8], hv1 = hb[hb8 + 1], hv2 = hb[hb8 + 2],
          hv3 = hb[hb8 + 3], hv4 = hb[hb8 + 4], hv5 = hb[hb8 + 5],
          hv6 = hb[hb8 + 6], hv7 = hb[hb8 + 7];
    // out k, tap d=8g+1+dd: xm = mv[k+7-dd], xp = pv[k+1+dd], dd ascending
    a0 = fmaf(hv0, mv7 + pv1, a0);
    a0 = fmaf(hv1, mv6 + pv2, a0);
    a0 = fmaf(hv2, mv5 + pv3, a0);
    a0 = fmaf(hv3, mv4 + pv4, a0);
    a0 = fmaf(hv4, mv3 + pv5, a0);
    a0 = fmaf(hv5, mv2 + pv6, a0);
    a0 = fmaf(hv6, mv1 + pv7, a0);
    a0 = fmaf(hv7, mv0 + pv8, a0);
    a1 = fmaf(hv0, mv8 + pv2, a1);
    a1 = fmaf(hv1, mv7 + pv3, a1);
    a1 = fmaf(hv2, mv6 + pv4, a1);
    a1 = fmaf(hv3, mv5 + pv5, a1);
    a1 = fmaf(hv4, mv4 + pv6, a1);
    a1 = fmaf(hv5, mv3 + pv7, a1);
    a1 = fmaf(hv6, mv2 + pv8, a1);
    a1 = fmaf(hv7, mv1 + pv9, a1);
    a2 = fmaf(hv0, mv9 + pv3, a2);
    a2 = fmaf(hv1, mv8 + pv4, a2);
    a2 = fmaf(hv2, mv7 + pv5, a2);
    a2 = fmaf(hv3, mv6 + pv6, a2);
    a2 = fmaf(hv4, mv5 + pv7, a2);
    a2 = fmaf(hv5, mv4 + pv8, a2);
    a2 = fmaf(hv6, mv3 + pv9, a2);
    a2 = fmaf(hv7, mv2 + pv10, a2);
    a3 = fmaf(hv0, mv10 + pv4, a3);
    a3 = fmaf(hv1, mv9 + pv5, a3);
    a3 = fmaf(hv2, mv8 + pv6, a3);
    a3 = fmaf(hv3, mv7 + pv7, a3);
    a3 = fmaf(hv4, mv6 + pv8, a3);
    a3 = fmaf(hv5, mv5 + pv9, a3);
    a3 = fmaf(hv6, mv4 + pv10, a3);
    a3 = fmaf(hv7, mv3 + pv11, a3);
    a4 = fmaf(hv0, mv11 + pv5, a4);
    a4 = fmaf(hv1, mv10 + pv6, a4);
    a4 = fmaf(hv2, mv9 + pv7, a4);
    a4 = fmaf(hv3, mv8 + pv8, a4);
    a4 = fmaf(hv4, mv7 + pv9, a4);
    a4 = fmaf(hv5, mv6 + pv10, a4);
    a4 = fmaf(hv6, mv5 + pv11, a4);
    a4 = fmaf(hv7, mv4 + pv12, a4);
    a5 = fmaf(hv0, mv12 + pv6, a5);
    a5 = fmaf(hv1, mv11 + pv7, a5);
    a5 = fmaf(hv2, mv10 + pv8, a5);
    a5 = fmaf(hv3, mv9 + pv9, a5);
    a5 = fmaf(hv4, mv8 + pv10, a5);
    a5 = fmaf(hv5, mv7 + pv11, a5);
    a5 = fmaf(hv6, mv6 + pv12, a5);
    a5 = fmaf(hv7, mv5 + pv13, a5);
    a6 = fmaf(hv0, mv13 + pv7, a6);
    a6 = fmaf(hv1, mv12 + pv8, a6);
    a6 = fmaf(hv2, mv11 + pv9, a6);
    a6 = fmaf(hv3, mv10 + pv10, a6);
    a6 = fmaf(hv4, mv9 + pv11, a6);
    a6 = fmaf(hv5, mv8 + pv12, a6);
    a6 = fmaf(hv6, mv7 + pv13, a6);
    a6 = fmaf(hv7, mv6 + pv14, a6);
    a7 = fmaf(hv0, mv14 + pv8, a7);
    a7 = fmaf(hv1, mv13 + pv9, a7);
    a7 = fmaf(hv2, mv12 + pv10, a7);
    a7 = fmaf(hv3, mv11 + pv11, a7);
    a7 = fmaf(hv4, mv10 + pv12, a7);
    a7 = fmaf(hv5, mv9 + pv13, a7);
    a7 = fmaf(hv6, mv8 + pv14, a7);
    a7 = fmaf(hv7, mv7 + pv15, a7);
  }
  int t = t0 + tid * 8;
  if (t < TAUD) {
    float4 o0 = make_float4(a0 * 0.1f, a1 * 0.1f, a2 * 0.1f, a3 * 0.1f);
    float4 o1 = make_float4(a4 * 0.1f, a5 * 0.1f, a6 * 0.1f, a7 * 0.1f);
    *reinterpret_cast<float4*>(&ynz[(size_t)b * TAUD + t]) = o0;
    *reinterpret_cast<float4*>(&ynz[(size_t)b * TAUD + t + 4]) = o1;
  }
}

// ---------------- final mix ----------------
__global__ __launch_bounds__(256) void k_final(const float* __restrict__ hpart,
                                               const float* __restrict__ ynz,
                                               const float* __restrict__ loud,
                                               float* __restrict__ out) {
  int idx = blockIdx.x * 256 + threadIdx.x;
  if (idx >= NBATCH * TAUD) return;
  int b = idx / TAUD, j = idx - b * TAUD;
  int i0, i1; float w;
  iparams(j, i0, i1, w);
  float env = __fadd_rn(__fmul_rn(loud[b * NT + i0], __fsub_rn(1.0f, w)),
                        __fmul_rn(loud[b * NT + i1], w));
  const size_t S = (size_t)NBATCH * TAUD;
  float hsum = __fadd_rn(__fadd_rn(__fadd_rn(hpart[idx], hpart[S + idx]),
                                   hpart[2 * S + idx]),
                         hpart[3 * S + idx]);
  out[idx] = __fmul_rn(__fadd_rn(hsum, ynz[idx]), env);
}

}  // namespace

extern "C" void kernel_launch(void* const* d_in, const int* in_sizes, int n_in,
                              void* d_out, int out_size, void* d_ws, size_t ws_size,
                              hipStream_t stream) {
  const float* z    = (const float*)d_in[0];
  const float* f0n  = (const float*)d_in[1];
  const float* loud = (const float*)d_in[2];
  const float* nz   = (const float*)d_in[3];
  const float* W1p  = (const float*)d_in[4];
  const float* b1p  = (const float*)d_in[5];
  const float* W2p  = (const float*)d_in[6];
  const float* b2p  = (const float*)d_in[7];
  const float* W1n  = (const float*)d_in[8];
  const float* b1n  = (const float*)d_in[9];
  const float* W2n  = (const float*)d_in[10];
  const float* b2n  = (const float*)d_in[11];
  float* out = (float*)d_out;
  float* ws  = (float*)d_ws;

  size_t off = 0;
  float* amp   = ws + off; off += (size_t)NBATCH * NT * NPART;      // 256,000
  float* nmag  = ws + off; off += (size_t)NBATCH * NT * NBINS;      // 1,024,000
  float* f0hz  = ws + off; off += (size_t)NBATCH * NT;              // 4,000
  float* mmw   = ws + off; off += (size_t)NBATCH * NBINS;           // 2,048
  float* G     = ws + off; off += (size_t)(LCONV + 1) * NBINS;      // 262,400
  float* hh    = ws + off; off += (size_t)NBATCH * (LCONV + 1);     // 8,200
  float* ynz   = ws + off; off += (size_t)NBATCH * TAUD;            // 704,000
  float* pref4 = ws + off; off += (size_t)NBATCH * NPART * 5500;    // 2,816,000
  float* hpart = ws + off; off += (size_t)4 * NBATCH * TAUD;        // 2,816,000
  (void)ws_size; (void)in_sizes; (void)n_in; (void)out_size;        // ~31.2 MB total

  double HI = log2(2093.0), LO = log2(32.7);
  float C1 = (float)(HI - LO), C2 = (float)LO;

  k_basis<<<LCONV + 1, 256, 0, stream>>>(G);
  k_f0<<<(NBATCH * NT + 255) / 256, 256, 0, stream>>>(f0n, f0hz, C1, C2);
  k_mlp<<<(NBATCH * NT) / 8, 256, 0, stream>>>(z, W1p, b1p, W2p, b2p,
                                               W1n, b1n, W2n, b2n, amp, nmag);
  k_mean<<<NBATCH, 256, 0, stream>>>(nmag, mmw);
  k_hc<<<LCONV + 1, 256, 0, stream>>>(mmw, G, hh);
  k_scan_top<<<NBATCH * NPART, 256, 0, stream>>>(f0hz, pref4);
  dim3 gh(22, NBATCH, 4);
  k_harm<<<gh, 256, 0, stream>>>(f0hz, amp, pref4, hpart);
  dim3 gc((TAUD + CT - 1) / CT, NBATCH);
  k_conv<<<gc, 128, 0, stream>>>(nz, hh, ynz);
  k_final<<<(NBATCH * TAUD + 255) / 256, 256, 0, stream>>>(hpart, ynz, loud, out);
}

// Round 7
// 203.958 us; speedup vs baseline: 2.2828x; 1.4488x over previous
//
#include <hip/hip_runtime.h>
#include <cmath>

// DDSP decoder, bit-exact-phase implementation.
// R7: LCONV 1024 -> 256 (h[n] ~ 1/(20 n^2) from piecewise-linear spectrum;
//     tail |delta| <= ~1e-4 << 0.015 margin). Conv work /4, k_basis /4.
//     k_conv reverted to the R5 shape (256 thr x 4 outputs, scalar b32
//     SoA-plane reads, h in LDS) -- R6's 128-thr variant was latency-bound
//     at 9% occupancy. Conv chain = rounding-identical prefix of R6's.

#define NBATCH 8
#define NT     500
#define ND     128
#define TAUD   88000
#define NPART  64
#define NBINS  256
#define NFREQ  44001
#define LCONV  256

namespace {

constexpr float  SCALE_TA = (float)(500.0 / 88000.0);   // lin_interp scale, fp32 like jnp
constexpr float  SCALE_NF = (float)(256.0 / 44001.0);
constexpr float  TWOPI_F  = (float)6.283185307179586476925286766559;
constexpr float  CANG     = (float)(6.283185307179586476925286766559 / 88000.0);
constexpr float  INV_SR   = 1.0f / 44100.0f;            // RN reciprocal
constexpr float  INV2PI_F = 0.15915494309189535f;       // RN(1/2pi)
constexpr float  PI2_HI   = 6.2831854820251464844f;     // RN(2pi) fp32
constexpr float  PI2_LO   = -1.7484556000744487e-7f;    // RN(2pi - PI2_HI)

__device__ __forceinline__ void iparams(int j, int& i0, int& i1, float& w) {
  float jf  = (float)j;
  float src = __fsub_rn(__fmul_rn(__fadd_rn(jf, 0.5f), SCALE_TA), 0.5f);
  src = fminf(fmaxf(src, 0.0f), 499.0f);
  int a = (int)src;            // floor (src >= 0)
  i0 = a;
  i1 = (a + 1 > 499) ? 499 : (a + 1);
  w  = __fsub_rn(src, (float)a);
}

// correctly-rounded x/44100 (Markstein: RN recip + 2 fma) == __fdiv_rn
__device__ __forceinline__ float div_sr(float x) {
  float q0 = __fmul_rn(x, INV_SR);
  float e  = __builtin_fmaf(-44100.0f, q0, x);
  return __builtin_fmaf(e, INV_SR, q0);
}

__device__ __forceinline__ float inc_val(const float* sf0, int j, float pf) {
  int i0, i1; float w;
  iparams(j, i0, i1, w);
  float fa = __fmul_rn(sf0[i0], pf);
  float fb = __fmul_rn(sf0[i1], pf);
  float fu = __fadd_rn(__fmul_rn(fa, __fsub_rn(1.0f, w)), __fmul_rn(fb, w));
  return div_sr(fu);
}

// sin of the fp32 value x (|x| up to ~3e5): float Cody-Waite reduce + v_sin.
__device__ __forceinline__ float sin_fast(float x) {
  float k = rintf(__fmul_rn(x, INV2PI_F));
  float r = __builtin_fmaf(-k, PI2_HI, x);
  r = __builtin_fmaf(-k, PI2_LO, r);
  return __sinf(r);
}

// ---------------- f0 (Hz) ----------------
__global__ __launch_bounds__(256) void k_f0(const float* __restrict__ f0n,
                                            float* __restrict__ f0hz,
                                            float C1, float C2) {
  int i = blockIdx.x * 256 + threadIdx.x;
  if (i < NBATCH * NT) {
    float x = __fadd_rn(__fmul_rn(f0n[i], C1), C2);
    f0hz[i] = (float)exp2((double)x);
  }
}

// ---------------- MLP heads (8 rows / block) ----------------
__global__ __launch_bounds__(256) void k_mlp(
    const float* __restrict__ z,
    const float* __restrict__ W1p, const float* __restrict__ b1p,
    const float* __restrict__ W2p, const float* __restrict__ b2p,
    const float* __restrict__ W1n, const float* __restrict__ b1n,
    const float* __restrict__ W2n, const float* __restrict__ b2n,
    float* __restrict__ amp, float* __restrict__ nmag) {
  int row0 = blockIdx.x * 8;
  int tid  = threadIdx.x;
  __shared__ float zs[8][ND];
  __shared__ float hp[8][256];
  __shared__ float hn[8][256];
  for (int i = tid; i < 8 * ND; i += 256) {
    int r = i >> 7, d = i & 127;
    zs[r][d] = z[(size_t)(row0 + r) * ND + d];
  }
  __syncthreads();
  float ap[8], an[8];
  float bp = b1p[tid], bn = b1n[tid];
#pragma unroll
  for (int r = 0; r < 8; ++r) { ap[r] = bp; an[r] = bn; }
  for (int d = 0; d < ND; ++d) {
    float w1 = W1p[d * 256 + tid];
    float w2 = W1n[d * 256 + tid];
#pragma unroll
    for (int r = 0; r < 8; ++r) {
      float zz = zs[r][d];
      ap[r] = fmaf(zz, w1, ap[r]);
      an[r] = fmaf(zz, w2, an[r]);
    }
  }
#pragma unroll
  for (int r = 0; r < 8; ++r) {
    hp[r][tid] = fmaxf(ap[r], 0.0f);
    hn[r][tid] = fmaxf(an[r], 0.0f);
  }
  __syncthreads();
  float a2[8];
  float bn2 = b2n[tid];
#pragma unroll
  for (int r = 0; r < 8; ++r) a2[r] = bn2;
  for (int h = 0; h < 256; ++h) {
    float w = W2n[h * 256 + tid];
#pragma unroll
    for (int r = 0; r < 8; ++r) a2[r] = fmaf(hn[r][h], w, a2[r]);
  }
#pragma unroll
  for (int r = 0; r < 8; ++r)
    nmag[(size_t)(row0 + r) * 256 + tid] = 1.0f / (1.0f + expf(-a2[r]));
  if (tid < 64) {
    float a1[8];
    float bp2 = b2p[tid];
#pragma unroll
    for (int r = 0; r < 8; ++r) a1[r] = bp2;
    for (int h = 0; h < 256; ++h) {
      float w = W2p[h * 64 + tid];
#pragma unroll
      for (int r = 0; r < 8; ++r) a1[r] = fmaf(hp[r][h], w, a1[r]);
    }
#pragma unroll
    for (int r = 0; r < 8; ++r)
      amp[(size_t)(row0 + r) * 64 + tid] = 1.0f / (1.0f + expf(-a1[r]));
  }
}

// ---------------- mean over frames (== mean of lin_interp, exact) ----------------
__global__ __launch_bounds__(256) void k_mean(const float* __restrict__ nmag,
                                              float* __restrict__ mm) {
  int b = blockIdx.x, k = threadIdx.x;
  float s = 0.0f;
  for (int t = 0; t < NT; ++t) s += nmag[((size_t)b * NT + t) * 256 + k];
  mm[b * 256 + k] = s * (1.0f / 500.0f);
}

// ---------------- basis G[n][i] = sum_k hat_i(k) * cos(2 pi n k / 88000) ----------------
__global__ __launch_bounds__(256) void k_basis(float* __restrict__ G) {
  int n = blockIdx.x;       // 0..LCONV
  int i = threadIdx.x;      // bin 0..255
  int start = 1, end = 43999;
  if (i > 0) {
    int s0 = (int)(((float)i - 0.5f) * 171.87890625f - 0.5f) - 4;
    if (s0 > start) start = s0;
  }
  int e0 = (int)(((float)i + 1.5f) * 171.87890625f - 0.5f) + 4;
  if (e0 < end) end = e0;
  float acc = 0.0f;
  int m = (n * start) % TAUD;
  for (int k = start; k <= end; ++k) {
    float kf  = (float)k;
    float src = __fsub_rn(__fmul_rn(__fadd_rn(kf, 0.5f), SCALE_NF), 0.5f);
    src = fminf(fmaxf(src, 0.0f), 255.0f);
    int i0 = (int)src;
    float w = __fsub_rn(src, (float)i0);
    float wt = 0.0f;
    if (i0 == i) wt = __fsub_rn(1.0f, w);
    int i1 = (i0 < 255) ? i0 + 1 : 255;
    if (i1 == i) wt = __fadd_rn(wt, w);
    acc = fmaf(wt, __cosf((float)m * CANG), acc);
    m += n; if (m >= TAUD) m -= TAUD;
  }
  G[n * 256 + i] = acc;
}

// ---------------- combine: h[b][n] = (F0 +- FN + 2*sum_i mm_i G[n][i]) / N ----------------
__global__ __launch_bounds__(256) void k_hc(const float* __restrict__ mm,
                                            const float* __restrict__ G,
                                            float* __restrict__ hh) {
  int n = blockIdx.x;       // 0..LCONV
  int tid = threadIdx.x;
  float g = G[n * 256 + tid];
  __shared__ float red[256];
  for (int b = 0; b < NBATCH; ++b) {
    red[tid] = mm[b * 256 + tid] * g;
    __syncthreads();
    for (int st = 128; st > 0; st >>= 1) {
      if (tid < st) red[tid] += red[tid + st];
      __syncthreads();
    }
    if (tid == 0) {
      float F0 = mm[b * 256 + 0];
      float src = __fsub_rn(__fmul_rn(__fadd_rn(44000.0f, 0.5f), SCALE_NF), 0.5f);
      src = fminf(fmaxf(src, 0.0f), 255.0f);
      int i0 = (int)src;
      float w = __fsub_rn(src, (float)i0);
      int i1 = (i0 < 255) ? i0 + 1 : 255;
      float FN = __fadd_rn(__fmul_rn(mm[b * 256 + i0], __fsub_rn(1.0f, w)),
                           __fmul_rn(mm[b * 256 + i1], w));
      float tot = 2.0f * red[0] + F0 + ((n & 1) ? -FN : FN);
      hh[b * (LCONV + 1) + n] = tot * (1.0f / 88000.0f);
    }
    __syncthreads();
  }
}

// ---------------- cumsum top levels: Brent-Kung (associative_scan DAG) ----------------
__global__ __launch_bounds__(256) void k_scan_top(const float* __restrict__ f0hz,
                                                  float* __restrict__ pref4) {
  int bp = blockIdx.x;
  int b = bp >> 6, p = bp & 63;
  float pf = (float)(p + 1);
  __shared__ float sf0[NT];
  __shared__ float lev[10992];
  int tid = threadIdx.x;
  for (int i = tid; i < NT; i += 256) sf0[i] = f0hz[b * NT + i];
  __syncthreads();
  for (int m = tid; m < 5500; m += 256) {
    float v[16];
#pragma unroll
    for (int t = 0; t < 16; ++t) v[t] = inc_val(sf0, m * 16 + t, pf);
    float s1[8];
#pragma unroll
    for (int t = 0; t < 8; ++t) s1[t] = __fadd_rn(v[2 * t], v[2 * t + 1]);
    float s2[4];
#pragma unroll
    for (int t = 0; t < 4; ++t) s2[t] = __fadd_rn(s1[2 * t], s1[2 * t + 1]);
    float s3a = __fadd_rn(s2[0], s2[1]);
    float s3b = __fadd_rn(s2[2], s2[3]);
    lev[m] = __fadd_rn(s3a, s3b);
  }
  __syncthreads();
  const int sizes[13] = {5500, 2750, 1375, 687, 343, 171, 85, 42, 21, 10, 5, 2, 1};
  const int offs[13]  = {0, 5500, 8250, 9625, 10312, 10655, 10826, 10911,
                         10953, 10974, 10984, 10989, 10991};
  for (int L = 1; L < 13; ++L) {
    int n = sizes[L];
    const float* src = lev + offs[L - 1];
    float* dst = lev + offs[L];
    for (int k2 = tid; k2 < n; k2 += 256)
      dst[k2] = __fadd_rn(src[2 * k2], src[2 * k2 + 1]);
    __syncthreads();
  }
  for (int L = 11; L >= 0; --L) {
    int n = sizes[L];
    float* cur = lev + offs[L];
    const float* up = lev + offs[L + 1];
    for (int idx = 1 + tid; idx < n; idx += 256) {
      float val;
      if (idx & 1) val = up[(idx - 1) >> 1];
      else         val = __fadd_rn(up[(idx >> 1) - 1], cur[idx]);
      cur[idx] = val;
    }
    __syncthreads();
  }
  for (int m = tid; m < 5500; m += 256)
    pref4[(size_t)bp * 5500 + m] = lev[m];
}

// ---------------- fused harmonic synth ----------------
__global__ __launch_bounds__(256) void k_harm(const float* __restrict__ f0hz,
                                              const float* __restrict__ amp,
                                              const float* __restrict__ pref4,
                                              float* __restrict__ hpart) {
  int chunk = blockIdx.x, b = blockIdx.y, g = blockIdx.z;
  int tid = threadIdx.x;
  int m = chunk * 256 + tid;
  bool act = (m < 5500);
  __shared__ float sf0[NT];
  for (int i = tid; i < NT; i += 256) sf0[i] = f0hz[b * NT + i];
  __syncthreads();
  int mm_ = act ? m : 0;
  int j0 = mm_ * 16;
  float wv[16], wm[16];
  unsigned damask = 0, dnmask = 0;
  int f = 0;
#pragma unroll
  for (int t = 0; t < 16; ++t) {
    int j = j0 + t;
    float jf = (float)j;
    float src = __fsub_rn(__fmul_rn(__fadd_rn(jf, 0.5f), SCALE_TA), 0.5f);
    src = fminf(fmaxf(src, 0.0f), 499.0f);
    int a = (int)src;
    if (t == 0) f = a;                 // i0 monotone nondecreasing in j
    wv[t] = __fsub_rn(src, (float)a);
    wm[t] = __fsub_rn(1.0f, wv[t]);
    damask |= (unsigned)(a - f) << t;  // in {0,1}
    int ni = (int)__fmul_rn(jf, SCALE_TA);
    ni = ni > 499 ? 499 : ni;
    dnmask |= (unsigned)(ni - f) << t; // in {0,1}
  }
  int f1 = (f + 1 > 499) ? 499 : f + 1;
  int f2 = (f + 2 > 499) ? 499 : f + 2;
  float s0 = sf0[f], s1 = sf0[f1], s2 = sf0[f2];

  float acc[16];
#pragma unroll
  for (int t = 0; t < 16; ++t) acc[t] = 0.0f;

  for (int pp = 0; pp < 16; ++pp) {
    int p = g * 16 + pp;
    float pf = (float)(p + 1);
    float fs0 = __fmul_rn(s0, pf);
    float fs1 = __fmul_rn(s1, pf);
    if (!(fs0 < 22050.0f) && !(fs1 < 22050.0f)) break;
    float fs2 = __fmul_rn(s2, pf);
    size_t pbase = ((size_t)(b * NPART + p)) * 5500;
    float left = (mm_ > 0) ? pref4[pbase + mm_ - 1] : 0.0f;
    float P4 = pref4[pbase + mm_];
    float v[16];
#pragma unroll
    for (int t = 0; t < 16; ++t) {
      bool d = (damask >> t) & 1;
      float fa = d ? fs1 : fs0;
      float fb = d ? fs2 : fs1;
      float fu = __fadd_rn(__fmul_rn(fa, wm[t]), __fmul_rn(fb, wv[t]));
      v[t] = div_sr(fu);
    }
    float s1t[8];
#pragma unroll
    for (int t = 0; t < 8; ++t) s1t[t] = __fadd_rn(v[2 * t], v[2 * t + 1]);
    float s2t[4];
#pragma unroll
    for (int t = 0; t < 4; ++t) s2t[t] = __fadd_rn(s1t[2 * t], s1t[2 * t + 1]);
    float s3_0 = __fadd_rn(s2t[0], s2t[1]);
    bool fz = (mm_ == 0);
    float l3_0 = fz ? s3_0 : __fadd_rn(left, s3_0);
    float l2_0 = fz ? s2t[0] : __fadd_rn(left, s2t[0]);
    float l2_1 = l3_0;
    float l2_2 = __fadd_rn(l3_0, s2t[2]);
    float l2_3 = P4;
    float l1_0 = fz ? s1t[0] : __fadd_rn(left, s1t[0]);
    float l1_1 = l2_0;
    float l1_2 = __fadd_rn(l2_0, s1t[2]);
    float l1_3 = l2_1;
    float l1_4 = __fadd_rn(l2_1, s1t[4]);
    float l1_5 = l2_2;
    float l1_6 = __fadd_rn(l2_2, s1t[6]);
    float l1_7 = l2_3;
    float ph[16];
    ph[0]  = fz ? v[0] : __fadd_rn(left, v[0]);
    ph[1]  = l1_0;
    ph[2]  = __fadd_rn(l1_0, v[2]);
    ph[3]  = l1_1;
    ph[4]  = __fadd_rn(l1_1, v[4]);
    ph[5]  = l1_2;
    ph[6]  = __fadd_rn(l1_2, v[6]);
    ph[7]  = l1_3;
    ph[8]  = __fadd_rn(l1_3, v[8]);
    ph[9]  = l1_4;
    ph[10] = __fadd_rn(l1_4, v[10]);
    ph[11] = l1_5;
    ph[12] = __fadd_rn(l1_5, v[12]);
    ph[13] = l1_6;
    ph[14] = __fadd_rn(l1_6, v[14]);
    ph[15] = l1_7;
    float ga0 = amp[((size_t)(b * NT + f)) * 64 + p];
    float ga1 = amp[((size_t)(b * NT + f1)) * 64 + p];
    float ga2 = amp[((size_t)(b * NT + f2)) * 64 + p];
#pragma unroll
    for (int t = 0; t < 16; ++t) {
      bool dn = (dnmask >> t) & 1;
      float fr = dn ? fs1 : fs0;
      if (fr < 22050.0f) {
        float x = __fmul_rn(ph[t], TWOPI_F);
        float s = sin_fast(x);
        bool d = (damask >> t) & 1;
        float lo = d ? ga1 : ga0;
        float hi = d ? ga2 : ga1;
        float au = __fadd_rn(__fmul_rn(lo, wm[t]), __fmul_rn(hi, wv[t]));
        acc[t] = __fadd_rn(acc[t], __fmul_rn(s, au));
      }
    }
  }
  if (act) {
    size_t obase = ((size_t)g * NBATCH + b) * TAUD + (size_t)j0;
#pragma unroll
    for (int t = 0; t < 16; ++t) hpart[obase + t] = acc[t];
  }
}

// ---------------- circular convolution (truncated +-LCONV=256) ----------------
// R5 shape: 256 thr x 4 outputs, SoA 4-plane LDS (plane[c][k]=x[4k+c],
// stride 392 = 8 mod 32), scalar b32 stride-1-lane reads (conflict-free),
// h[1..256] in LDS (broadcast). Per-output chain: h0*x then ascending-d
// fmaf(h, xm+xp, acc) -> rounding-identical prefix of the L=1024 chain.
#define CT    1024
#define PSTR  392
__global__ __launch_bounds__(256) void k_conv(const float* __restrict__ noise,
                                              const float* __restrict__ hh,
                                              float* __restrict__ ynz) {
  int b = blockIdx.y;
  int t0 = blockIdx.x * CT;
  int tid = threadIdx.x;
  __shared__ float xsp[4 * PSTR];     // window x[t0-256 .. t0+CT+256)
  __shared__ float hsh[LCONV];        // h[1..256]
  const float* hb = hh + b * (LCONV + 1);
  for (int i = tid; i < CT + 2 * LCONV; i += 256) {
    int j = t0 - LCONV + i;
    if (j < 0) j += TAUD;
    else if (j >= TAUD) j -= TAUD;
    xsp[(i & 3) * PSTR + (i >> 2)] = noise[(size_t)b * TAUD + j];
  }
  hsh[tid] = hb[1 + tid];             // LCONV == blockDim == 256
  __syncthreads();
  float h0 = hb[0];
  int B4 = tid + 64;                  // plane row of x[t0 + 4*tid]
  float a0 = h0 * xsp[0 * PSTR + B4];
  float a1 = h0 * xsp[1 * PSTR + B4];
  float a2 = h0 * xsp[2 * PSTR + B4];
  float a3 = h0 * xsp[3 * PSTR + B4];
  for (int g = 0; g < 32; ++g) {      // taps d = 8g+1 .. 8g+8
    int km = tid + 62 - 2 * g;        // minus side base (plane k)
    int kp = tid + 64 + 2 * g;        // plus side base
    // mv[u] = xs[B-8g-8+u] u=0..10 ; pv[u] = xs[B+8g+u] u=1..11
    float mv0 = xsp[0 * PSTR + km],     mv1 = xsp[1 * PSTR + km];
    float mv2 = xsp[2 * PSTR + km],     mv3 = xsp[3 * PSTR + km];
    float mv4 = xsp[0 * PSTR + km + 1], mv5 = xsp[1 * PSTR + km + 1];
    float mv6 = xsp[2 * PSTR + km + 1], mv7 = xsp[3 * PSTR + km + 1];
    float mv8 = xsp[0 * PSTR + km + 2], mv9 = xsp[1 * PSTR + km + 2];
    float mv10 = xsp[2 * PSTR + km + 2];
    float pv1 = xsp[1 * PSTR + kp],     pv2 = xsp[2 * PSTR + kp];
    float pv3 = xsp[3 * PSTR + kp];
    float pv4 = xsp[0 * PSTR + kp + 1], pv5 = xsp[1 * PSTR + kp + 1];
    float pv6 = xsp[2 * PSTR + kp + 1], pv7 = xsp[3 * PSTR + kp + 1];
    float pv8 = xsp[0 * PSTR + kp + 2], pv9 = xsp[1 * PSTR + kp + 2];
    float pv10 = xsp[2 * PSTR + kp + 2], pv11 = xsp[3 * PSTR + kp + 2];
    int hbase = 8 * g;                // uniform -> broadcast reads
    float hv0 = hsh[hbase + 0], hv1 = hsh[hbase + 1];
    float hv2 = hsh[hbase + 2], hv3 = hsh[hbase + 3];
    float hv4 = hsh[hbase + 4], hv5 = hsh[hbase + 5];
    float hv6 = hsh[hbase + 6], hv7 = hsh[hbase + 7];
    // out k, tap d=8g+1+dd: xm = mv[k+7-dd], xp = pv[k+1+dd], dd ascending
    a0 = fmaf(hv0, mv7 + pv1, a0);
    a0 = fmaf(hv1, mv6 + pv2, a0);
    a0 = fmaf(hv2, mv5 + pv3, a0);
    a0 = fmaf(hv3, mv4 + pv4, a0);
    a0 = fmaf(hv4, mv3 + pv5, a0);
    a0 = fmaf(hv5, mv2 + pv6, a0);
    a0 = fmaf(hv6, mv1 + pv7, a0);
    a0 = fmaf(hv7, mv0 + pv8, a0);
    a1 = fmaf(hv0, mv8 + pv2, a1);
    a1 = fmaf(hv1, mv7 + pv3, a1);
    a1 = fmaf(hv2, mv6 + pv4, a1);
    a1 = fmaf(hv3, mv5 + pv5, a1);
    a1 = fmaf(hv4, mv4 + pv6, a1);
    a1 = fmaf(hv5, mv3 + pv7, a1);
    a1 = fmaf(hv6, mv2 + pv8, a1);
    a1 = fmaf(hv7, mv1 + pv9, a1);
    a2 = fmaf(hv0, mv9 + pv3, a2);
    a2 = fmaf(hv1, mv8 + pv4, a2);
    a2 = fmaf(hv2, mv7 + pv5, a2);
    a2 = fmaf(hv3, mv6 + pv6, a2);
    a2 = fmaf(hv4, mv5 + pv7, a2);
    a2 = fmaf(hv5, mv4 + pv8, a2);
    a2 = fmaf(hv6, mv3 + pv9, a2);
    a2 = fmaf(hv7, mv2 + pv10, a2);
    a3 = fmaf(hv0, mv10 + pv4, a3);
    a3 = fmaf(hv1, mv9 + pv5, a3);
    a3 = fmaf(hv2, mv8 + pv6, a3);
    a3 = fmaf(hv3, mv7 + pv7, a3);
    a3 = fmaf(hv4, mv6 + pv8, a3);
    a3 = fmaf(hv5, mv5 + pv9, a3);
    a3 = fmaf(hv6, mv4 + pv10, a3);
    a3 = fmaf(hv7, mv3 + pv11, a3);
  }
  int t = t0 + tid * 4;
  if (t < TAUD) {                     // TAUD%4==0 -> all 4 valid together
    float4 o = make_float4(a0 * 0.1f, a1 * 0.1f, a2 * 0.1f, a3 * 0.1f);
    *reinterpret_cast<float4*>(&ynz[(size_t)b * TAUD + t]) = o;
  }
}

// ---------------- final mix ----------------
__global__ __launch_bounds__(256) void k_final(const float* __restrict__ hpart,
                                               const float* __restrict__ ynz,
                                               const float* __restrict__ loud,
                                               float* __restrict__ out) {
  int idx = blockIdx.x * 256 + threadIdx.x;
  if (idx >= NBATCH * TAUD) return;
  int b = idx / TAUD, j = idx - b * TAUD;
  int i0, i1; float w;
  iparams(j, i0, i1, w);
  float env = __fadd_rn(__fmul_rn(loud[b * NT + i0], __fsub_rn(1.0f, w)),
                        __fmul_rn(loud[b * NT + i1], w));
  const size_t S = (size_t)NBATCH * TAUD;
  float hsum = __fadd_rn(__fadd_rn(__fadd_rn(hpart[idx], hpart[S + idx]),
                                   hpart[2 * S + idx]),
                         hpart[3 * S + idx]);
  out[idx] = __fmul_rn(__fadd_rn(hsum, ynz[idx]), env);
}

}  // namespace

extern "C" void kernel_launch(void* const* d_in, const int* in_sizes, int n_in,
                              void* d_out, int out_size, void* d_ws, size_t ws_size,
                              hipStream_t stream) {
  const float* z    = (const float*)d_in[0];
  const float* f0n  = (const float*)d_in[1];
  const float* loud = (const float*)d_in[2];
  const float* nz   = (const float*)d_in[3];
  const float* W1p  = (const float*)d_in[4];
  const float* b1p  = (const float*)d_in[5];
  const float* W2p  = (const float*)d_in[6];
  const float* b2p  = (const float*)d_in[7];
  const float* W1n  = (const float*)d_in[8];
  const float* b1n  = (const float*)d_in[9];
  const float* W2n  = (const float*)d_in[10];
  const float* b2n  = (const float*)d_in[11];
  float* out = (float*)d_out;
  float* ws  = (float*)d_ws;

  size_t off = 0;
  float* amp   = ws + off; off += (size_t)NBATCH * NT * NPART;      // 256,000
  float* nmag  = ws + off; off += (size_t)NBATCH * NT * NBINS;      // 1,024,000
  float* f0hz  = ws + off; off += (size_t)NBATCH * NT;              // 4,000
  float* mmw   = ws + off; off += (size_t)NBATCH * NBINS;           // 2,048
  float* G     = ws + off; off += (size_t)(LCONV + 1) * NBINS;      // 65,792
  float* hh    = ws + off; off += (size_t)NBATCH * (LCONV + 1);     // 2,056
  float* ynz   = ws + off; off += (size_t)NBATCH * TAUD;            // 704,000
  float* pref4 = ws + off; off += (size_t)NBATCH * NPART * 5500;    // 2,816,000
  float* hpart = ws + off; off += (size_t)4 * NBATCH * TAUD;        // 2,816,000
  (void)ws_size; (void)in_sizes; (void)n_in; (void)out_size;        // ~30 MB total

  double HI = log2(2093.0), LO = log2(32.7);
  float C1 = (float)(HI - LO), C2 = (float)LO;

  k_basis<<<LCONV + 1, 256, 0, stream>>>(G);
  k_f0<<<(NBATCH * NT + 255) / 256, 256, 0, stream>>>(f0n, f0hz, C1, C2);
  k_mlp<<<(NBATCH * NT) / 8, 256, 0, stream>>>(z, W1p, b1p, W2p, b2p,
                                               W1n, b1n, W2n, b2n, amp, nmag);
  k_mean<<<NBATCH, 256, 0, stream>>>(nmag, mmw);
  k_hc<<<LCONV + 1, 256, 0, stream>>>(mmw, G, hh);
  k_scan_top<<<NBATCH * NPART, 256, 0, stream>>>(f0hz, pref4);
  dim3 gh(22, NBATCH, 4);
  k_harm<<<gh, 256, 0, stream>>>(f0hz, amp, pref4, hpart);
  dim3 gc((TAUD + CT - 1) / CT, NBATCH);
  k_conv<<<gc, 256, 0, stream>>>(nz, hh, ynz);
  k_final<<<(NBATCH * TAUD + 255) / 256, 256, 0, stream>>>(hpart, ynz, loud, out);
}

// Round 8
// 201.086 us; speedup vs baseline: 2.3154x; 1.0143x over previous
//
#include <hip/hip_runtime.h>
#include <cmath>

// DDSP decoder, bit-exact-phase implementation.
// R8: k_mlp 8->4 rows/block (grid 500->1000, occupancy 2->4 blocks/CU) +
//     unroll-4 on reduction loops for load ILP. Per-output accumulation
//     order unchanged -> amp/nmag bit-identical.

#define NBATCH 8
#define NT     500
#define ND     128
#define TAUD   88000
#define NPART  64
#define NBINS  256
#define NFREQ  44001
#define LCONV  256
#define MROWS  4

namespace {

constexpr float  SCALE_TA = (float)(500.0 / 88000.0);   // lin_interp scale, fp32 like jnp
constexpr float  SCALE_NF = (float)(256.0 / 44001.0);
constexpr float  TWOPI_F  = (float)6.283185307179586476925286766559;
constexpr float  CANG     = (float)(6.283185307179586476925286766559 / 88000.0);
constexpr float  INV_SR   = 1.0f / 44100.0f;            // RN reciprocal
constexpr float  INV2PI_F = 0.15915494309189535f;       // RN(1/2pi)
constexpr float  PI2_HI   = 6.2831854820251464844f;     // RN(2pi) fp32
constexpr float  PI2_LO   = -1.7484556000744487e-7f;    // RN(2pi - PI2_HI)

__device__ __forceinline__ void iparams(int j, int& i0, int& i1, float& w) {
  float jf  = (float)j;
  float src = __fsub_rn(__fmul_rn(__fadd_rn(jf, 0.5f), SCALE_TA), 0.5f);
  src = fminf(fmaxf(src, 0.0f), 499.0f);
  int a = (int)src;            // floor (src >= 0)
  i0 = a;
  i1 = (a + 1 > 499) ? 499 : (a + 1);
  w  = __fsub_rn(src, (float)a);
}

// correctly-rounded x/44100 (Markstein: RN recip + 2 fma) == __fdiv_rn
__device__ __forceinline__ float div_sr(float x) {
  float q0 = __fmul_rn(x, INV_SR);
  float e  = __builtin_fmaf(-44100.0f, q0, x);
  return __builtin_fmaf(e, INV_SR, q0);
}

__device__ __forceinline__ float inc_val(const float* sf0, int j, float pf) {
  int i0, i1; float w;
  iparams(j, i0, i1, w);
  float fa = __fmul_rn(sf0[i0], pf);
  float fb = __fmul_rn(sf0[i1], pf);
  float fu = __fadd_rn(__fmul_rn(fa, __fsub_rn(1.0f, w)), __fmul_rn(fb, w));
  return div_sr(fu);
}

// sin of the fp32 value x (|x| up to ~3e5): float Cody-Waite reduce + v_sin.
__device__ __forceinline__ float sin_fast(float x) {
  float k = rintf(__fmul_rn(x, INV2PI_F));
  float r = __builtin_fmaf(-k, PI2_HI, x);
  r = __builtin_fmaf(-k, PI2_LO, r);
  return __sinf(r);
}

// ---------------- f0 (Hz) ----------------
__global__ __launch_bounds__(256) void k_f0(const float* __restrict__ f0n,
                                            float* __restrict__ f0hz,
                                            float C1, float C2) {
  int i = blockIdx.x * 256 + threadIdx.x;
  if (i < NBATCH * NT) {
    float x = __fadd_rn(__fmul_rn(f0n[i], C1), C2);
    f0hz[i] = (float)exp2((double)x);
  }
}

// ---------------- MLP heads (MROWS rows / block) ----------------
__global__ __launch_bounds__(256) void k_mlp(
    const float* __restrict__ z,
    const float* __restrict__ W1p, const float* __restrict__ b1p,
    const float* __restrict__ W2p, const float* __restrict__ b2p,
    const float* __restrict__ W1n, const float* __restrict__ b1n,
    const float* __restrict__ W2n, const float* __restrict__ b2n,
    float* __restrict__ amp, float* __restrict__ nmag) {
  int row0 = blockIdx.x * MROWS;
  int tid  = threadIdx.x;
  __shared__ float zs[MROWS][ND];
  __shared__ float hp[MROWS][256];
  __shared__ float hn[MROWS][256];
  for (int i = tid; i < MROWS * ND; i += 256) {
    int r = i >> 7, d = i & 127;
    zs[r][d] = z[(size_t)(row0 + r) * ND + d];
  }
  __syncthreads();
  float ap[MROWS], an[MROWS];
  float bp = b1p[tid], bn = b1n[tid];
#pragma unroll
  for (int r = 0; r < MROWS; ++r) { ap[r] = bp; an[r] = bn; }
#pragma unroll 4
  for (int d = 0; d < ND; ++d) {
    float w1 = W1p[d * 256 + tid];
    float w2 = W1n[d * 256 + tid];
#pragma unroll
    for (int r = 0; r < MROWS; ++r) {
      float zz = zs[r][d];
      ap[r] = fmaf(zz, w1, ap[r]);
      an[r] = fmaf(zz, w2, an[r]);
    }
  }
#pragma unroll
  for (int r = 0; r < MROWS; ++r) {
    hp[r][tid] = fmaxf(ap[r], 0.0f);
    hn[r][tid] = fmaxf(an[r], 0.0f);
  }
  __syncthreads();
  float a2[MROWS];
  float bn2 = b2n[tid];
#pragma unroll
  for (int r = 0; r < MROWS; ++r) a2[r] = bn2;
#pragma unroll 4
  for (int h = 0; h < 256; ++h) {
    float w = W2n[h * 256 + tid];
#pragma unroll
    for (int r = 0; r < MROWS; ++r) a2[r] = fmaf(hn[r][h], w, a2[r]);
  }
#pragma unroll
  for (int r = 0; r < MROWS; ++r)
    nmag[(size_t)(row0 + r) * 256 + tid] = 1.0f / (1.0f + expf(-a2[r]));
  if (tid < 64) {
    float a1[MROWS];
    float bp2 = b2p[tid];
#pragma unroll
    for (int r = 0; r < MROWS; ++r) a1[r] = bp2;
#pragma unroll 4
    for (int h = 0; h < 256; ++h) {
      float w = W2p[h * 64 + tid];
#pragma unroll
      for (int r = 0; r < MROWS; ++r) a1[r] = fmaf(hp[r][h], w, a1[r]);
    }
#pragma unroll
    for (int r = 0; r < MROWS; ++r)
      amp[(size_t)(row0 + r) * 64 + tid] = 1.0f / (1.0f + expf(-a1[r]));
  }
}

// ---------------- mean over frames (== mean of lin_interp, exact) ----------------
__global__ __launch_bounds__(256) void k_mean(const float* __restrict__ nmag,
                                              float* __restrict__ mm) {
  int b = blockIdx.x, k = threadIdx.x;
  float s = 0.0f;
  for (int t = 0; t < NT; ++t) s += nmag[((size_t)b * NT + t) * 256 + k];
  mm[b * 256 + k] = s * (1.0f / 500.0f);
}

// ---------------- basis G[n][i] = sum_k hat_i(k) * cos(2 pi n k / 88000) ----------------
__global__ __launch_bounds__(256) void k_basis(float* __restrict__ G) {
  int n = blockIdx.x;       // 0..LCONV
  int i = threadIdx.x;      // bin 0..255
  int start = 1, end = 43999;
  if (i > 0) {
    int s0 = (int)(((float)i - 0.5f) * 171.87890625f - 0.5f) - 4;
    if (s0 > start) start = s0;
  }
  int e0 = (int)(((float)i + 1.5f) * 171.87890625f - 0.5f) + 4;
  if (e0 < end) end = e0;
  float acc = 0.0f;
  int m = (n * start) % TAUD;
  for (int k = start; k <= end; ++k) {
    float kf  = (float)k;
    float src = __fsub_rn(__fmul_rn(__fadd_rn(kf, 0.5f), SCALE_NF), 0.5f);
    src = fminf(fmaxf(src, 0.0f), 255.0f);
    int i0 = (int)src;
    float w = __fsub_rn(src, (float)i0);
    float wt = 0.0f;
    if (i0 == i) wt = __fsub_rn(1.0f, w);
    int i1 = (i0 < 255) ? i0 + 1 : 255;
    if (i1 == i) wt = __fadd_rn(wt, w);
    acc = fmaf(wt, __cosf((float)m * CANG), acc);
    m += n; if (m >= TAUD) m -= TAUD;
  }
  G[n * 256 + i] = acc;
}

// ---------------- combine: h[b][n] = (F0 +- FN + 2*sum_i mm_i G[n][i]) / N ----------------
__global__ __launch_bounds__(256) void k_hc(const float* __restrict__ mm,
                                            const float* __restrict__ G,
                                            float* __restrict__ hh) {
  int n = blockIdx.x;       // 0..LCONV
  int tid = threadIdx.x;
  float g = G[n * 256 + tid];
  __shared__ float red[256];
  for (int b = 0; b < NBATCH; ++b) {
    red[tid] = mm[b * 256 + tid] * g;
    __syncthreads();
    for (int st = 128; st > 0; st >>= 1) {
      if (tid < st) red[tid] += red[tid + st];
      __syncthreads();
    }
    if (tid == 0) {
      float F0 = mm[b * 256 + 0];
      float src = __fsub_rn(__fmul_rn(__fadd_rn(44000.0f, 0.5f), SCALE_NF), 0.5f);
      src = fminf(fmaxf(src, 0.0f), 255.0f);
      int i0 = (int)src;
      float w = __fsub_rn(src, (float)i0);
      int i1 = (i0 < 255) ? i0 + 1 : 255;
      float FN = __fadd_rn(__fmul_rn(mm[b * 256 + i0], __fsub_rn(1.0f, w)),
                           __fmul_rn(mm[b * 256 + i1], w));
      float tot = 2.0f * red[0] + F0 + ((n & 1) ? -FN : FN);
      hh[b * (LCONV + 1) + n] = tot * (1.0f / 88000.0f);
    }
    __syncthreads();
  }
}

// ---------------- cumsum top levels: Brent-Kung (associative_scan DAG) ----------------
__global__ __launch_bounds__(256) void k_scan_top(const float* __restrict__ f0hz,
                                                  float* __restrict__ pref4) {
  int bp = blockIdx.x;
  int b = bp >> 6, p = bp & 63;
  float pf = (float)(p + 1);
  __shared__ float sf0[NT];
  __shared__ float lev[10992];
  int tid = threadIdx.x;
  for (int i = tid; i < NT; i += 256) sf0[i] = f0hz[b * NT + i];
  __syncthreads();
  for (int m = tid; m < 5500; m += 256) {
    float v[16];
#pragma unroll
    for (int t = 0; t < 16; ++t) v[t] = inc_val(sf0, m * 16 + t, pf);
    float s1[8];
#pragma unroll
    for (int t = 0; t < 8; ++t) s1[t] = __fadd_rn(v[2 * t], v[2 * t + 1]);
    float s2[4];
#pragma unroll
    for (int t = 0; t < 4; ++t) s2[t] = __fadd_rn(s1[2 * t], s1[2 * t + 1]);
    float s3a = __fadd_rn(s2[0], s2[1]);
    float s3b = __fadd_rn(s2[2], s2[3]);
    lev[m] = __fadd_rn(s3a, s3b);
  }
  __syncthreads();
  const int sizes[13] = {5500, 2750, 1375, 687, 343, 171, 85, 42, 21, 10, 5, 2, 1};
  const int offs[13]  = {0, 5500, 8250, 9625, 10312, 10655, 10826, 10911,
                         10953, 10974, 10984, 10989, 10991};
  for (int L = 1; L < 13; ++L) {
    int n = sizes[L];
    const float* src = lev + offs[L - 1];
    float* dst = lev + offs[L];
    for (int k2 = tid; k2 < n; k2 += 256)
      dst[k2] = __fadd_rn(src[2 * k2], src[2 * k2 + 1]);
    __syncthreads();
  }
  for (int L = 11; L >= 0; --L) {
    int n = sizes[L];
    float* cur = lev + offs[L];
    const float* up = lev + offs[L + 1];
    for (int idx = 1 + tid; idx < n; idx += 256) {
      float val;
      if (idx & 1) val = up[(idx - 1) >> 1];
      else         val = __fadd_rn(up[(idx >> 1) - 1], cur[idx]);
      cur[idx] = val;
    }
    __syncthreads();
  }
  for (int m = tid; m < 5500; m += 256)
    pref4[(size_t)bp * 5500 + m] = lev[m];
}

// ---------------- fused harmonic synth ----------------
__global__ __launch_bounds__(256) void k_harm(const float* __restrict__ f0hz,
                                              const float* __restrict__ amp,
                                              const float* __restrict__ pref4,
                                              float* __restrict__ hpart) {
  int chunk = blockIdx.x, b = blockIdx.y, g = blockIdx.z;
  int tid = threadIdx.x;
  int m = chunk * 256 + tid;
  bool act = (m < 5500);
  __shared__ float sf0[NT];
  for (int i = tid; i < NT; i += 256) sf0[i] = f0hz[b * NT + i];
  __syncthreads();
  int mm_ = act ? m : 0;
  int j0 = mm_ * 16;
  float wv[16], wm[16];
  unsigned damask = 0, dnmask = 0;
  int f = 0;
#pragma unroll
  for (int t = 0; t < 16; ++t) {
    int j = j0 + t;
    float jf = (float)j;
    float src = __fsub_rn(__fmul_rn(__fadd_rn(jf, 0.5f), SCALE_TA), 0.5f);
    src = fminf(fmaxf(src, 0.0f), 499.0f);
    int a = (int)src;
    if (t == 0) f = a;                 // i0 monotone nondecreasing in j
    wv[t] = __fsub_rn(src, (float)a);
    wm[t] = __fsub_rn(1.0f, wv[t]);
    damask |= (unsigned)(a - f) << t;  // in {0,1}
    int ni = (int)__fmul_rn(jf, SCALE_TA);
    ni = ni > 499 ? 499 : ni;
    dnmask |= (unsigned)(ni - f) << t; // in {0,1}
  }
  int f1 = (f + 1 > 499) ? 499 : f + 1;
  int f2 = (f + 2 > 499) ? 499 : f + 2;
  float s0 = sf0[f], s1 = sf0[f1], s2 = sf0[f2];

  float acc[16];
#pragma unroll
  for (int t = 0; t < 16; ++t) acc[t] = 0.0f;

  for (int pp = 0; pp < 16; ++pp) {
    int p = g * 16 + pp;
    float pf = (float)(p + 1);
    float fs0 = __fmul_rn(s0, pf);
    float fs1 = __fmul_rn(s1, pf);
    if (!(fs0 < 22050.0f) && !(fs1 < 22050.0f)) break;
    float fs2 = __fmul_rn(s2, pf);
    size_t pbase = ((size_t)(b * NPART + p)) * 5500;
    float left = (mm_ > 0) ? pref4[pbase + mm_ - 1] : 0.0f;
    float P4 = pref4[pbase + mm_];
    float v[16];
#pragma unroll
    for (int t = 0; t < 16; ++t) {
      bool d = (damask >> t) & 1;
      float fa = d ? fs1 : fs0;
      float fb = d ? fs2 : fs1;
      float fu = __fadd_rn(__fmul_rn(fa, wm[t]), __fmul_rn(fb, wv[t]));
      v[t] = div_sr(fu);
    }
    float s1t[8];
#pragma unroll
    for (int t = 0; t < 8; ++t) s1t[t] = __fadd_rn(v[2 * t], v[2 * t + 1]);
    float s2t[4];
#pragma unroll
    for (int t = 0; t < 4; ++t) s2t[t] = __fadd_rn(s1t[2 * t], s1t[2 * t + 1]);
    float s3_0 = __fadd_rn(s2t[0], s2t[1]);
    bool fz = (mm_ == 0);
    float l3_0 = fz ? s3_0 : __fadd_rn(left, s3_0);
    float l2_0 = fz ? s2t[0] : __fadd_rn(left, s2t[0]);
    float l2_1 = l3_0;
    float l2_2 = __fadd_rn(l3_0, s2t[2]);
    float l2_3 = P4;
    float l1_0 = fz ? s1t[0] : __fadd_rn(left, s1t[0]);
    float l1_1 = l2_0;
    float l1_2 = __fadd_rn(l2_0, s1t[2]);
    float l1_3 = l2_1;
    float l1_4 = __fadd_rn(l2_1, s1t[4]);
    float l1_5 = l2_2;
    float l1_6 = __fadd_rn(l2_2, s1t[6]);
    float l1_7 = l2_3;
    float ph[16];
    ph[0]  = fz ? v[0] : __fadd_rn(left, v[0]);
    ph[1]  = l1_0;
    ph[2]  = __fadd_rn(l1_0, v[2]);
    ph[3]  = l1_1;
    ph[4]  = __fadd_rn(l1_1, v[4]);
    ph[5]  = l1_2;
    ph[6]  = __fadd_rn(l1_2, v[6]);
    ph[7]  = l1_3;
    ph[8]  = __fadd_rn(l1_3, v[8]);
    ph[9]  = l1_4;
    ph[10] = __fadd_rn(l1_4, v[10]);
    ph[11] = l1_5;
    ph[12] = __fadd_rn(l1_5, v[12]);
    ph[13] = l1_6;
    ph[14] = __fadd_rn(l1_6, v[14]);
    ph[15] = l1_7;
    float ga0 = amp[((size_t)(b * NT + f)) * 64 + p];
    float ga1 = amp[((size_t)(b * NT + f1)) * 64 + p];
    float ga2 = amp[((size_t)(b * NT + f2)) * 64 + p];
#pragma unroll
    for (int t = 0; t < 16; ++t) {
      bool dn = (dnmask >> t) & 1;
      float fr = dn ? fs1 : fs0;
      if (fr < 22050.0f) {
        float x = __fmul_rn(ph[t], TWOPI_F);
        float s = sin_fast(x);
        bool d = (damask >> t) & 1;
        float lo = d ? ga1 : ga0;
        float hi = d ? ga2 : ga1;
        float au = __fadd_rn(__fmul_rn(lo, wm[t]), __fmul_rn(hi, wv[t]));
        acc[t] = __fadd_rn(acc[t], __fmul_rn(s, au));
      }
    }
  }
  if (act) {
    size_t obase = ((size_t)g * NBATCH + b) * TAUD + (size_t)j0;
#pragma unroll
    for (int t = 0; t < 16; ++t) hpart[obase + t] = acc[t];
  }
}

// ---------------- circular convolution (truncated +-LCONV=256) ----------------
#define CT    1024
#define PSTR  392
__global__ __launch_bounds__(256) void k_conv(const float* __restrict__ noise,
                                              const float* __restrict__ hh,
                                              float* __restrict__ ynz) {
  int b = blockIdx.y;
  int t0 = blockIdx.x * CT;
  int tid = threadIdx.x;
  __shared__ float xsp[4 * PSTR];     // window x[t0-256 .. t0+CT+256)
  __shared__ float hsh[LCONV];        // h[1..256]
  const float* hb = hh + b * (LCONV + 1);
  for (int i = tid; i < CT + 2 * LCONV; i += 256) {
    int j = t0 - LCONV + i;
    if (j < 0) j += TAUD;
    else if (j >= TAUD) j -= TAUD;
    xsp[(i & 3) * PSTR + (i >> 2)] = noise[(size_t)b * TAUD + j];
  }
  hsh[tid] = hb[1 + tid];             // LCONV == blockDim == 256
  __syncthreads();
  float h0 = hb[0];
  int B4 = tid + 64;                  // plane row of x[t0 + 4*tid]
  float a0 = h0 * xsp[0 * PSTR + B4];
  float a1 = h0 * xsp[1 * PSTR + B4];
  float a2 = h0 * xsp[2 * PSTR + B4];
  float a3 = h0 * xsp[3 * PSTR + B4];
  for (int g = 0; g < 32; ++g) {      // taps d = 8g+1 .. 8g+8
    int km = tid + 62 - 2 * g;        // minus side base (plane k)
    int kp = tid + 64 + 2 * g;        // plus side base
    float mv0 = xsp[0 * PSTR + km],     mv1 = xsp[1 * PSTR + km];
    float mv2 = xsp[2 * PSTR + km],     mv3 = xsp[3 * PSTR + km];
    float mv4 = xsp[0 * PSTR + km + 1], mv5 = xsp[1 * PSTR + km + 1];
    float mv6 = xsp[2 * PSTR + km + 1], mv7 = xsp[3 * PSTR + km + 1];
    float mv8 = xsp[0 * PSTR + km + 2], mv9 = xsp[1 * PSTR + km + 2];
    float mv10 = xsp[2 * PSTR + km + 2];
    float pv1 = xsp[1 * PSTR + kp],     pv2 = xsp[2 * PSTR + kp];
    float pv3 = xsp[3 * PSTR + kp];
    float pv4 = xsp[0 * PSTR + kp + 1], pv5 = xsp[1 * PSTR + kp + 1];
    float pv6 = xsp[2 * PSTR + kp + 1], pv7 = xsp[3 * PSTR + kp + 1];
    float pv8 = xsp[0 * PSTR + kp + 2], pv9 = xsp[1 * PSTR + kp + 2];
    float pv10 = xsp[2 * PSTR + kp + 2], pv11 = xsp[3 * PSTR + kp + 2];
    int hbase = 8 * g;                // uniform -> broadcast reads
    float hv0 = hsh[hbase + 0], hv1 = hsh[hbase + 1];
    float hv2 = hsh[hbase + 2], hv3 = hsh[hbase + 3];
    float hv4 = hsh[hbase + 4], hv5 = hsh[hbase + 5];
    float hv6 = hsh[hbase + 6], hv7 = hsh[hbase + 7];
    a0 = fmaf(hv0, mv7 + pv1, a0);
    a0 = fmaf(hv1, mv6 + pv2, a0);
    a0 = fmaf(hv2, mv5 + pv3, a0);
    a0 = fmaf(hv3, mv4 + pv4, a0);
    a0 = fmaf(hv4, mv3 + pv5, a0);
    a0 = fmaf(hv5, mv2 + pv6, a0);
    a0 = fmaf(hv6, mv1 + pv7, a0);
    a0 = fmaf(hv7, mv0 + pv8, a0);
    a1 = fmaf(hv0, mv8 + pv2, a1);
    a1 = fmaf(hv1, mv7 + pv3, a1);
    a1 = fmaf(hv2, mv6 + pv4, a1);
    a1 = fmaf(hv3, mv5 + pv5, a1);
    a1 = fmaf(hv4, mv4 + pv6, a1);
    a1 = fmaf(hv5, mv3 + pv7, a1);
    a1 = fmaf(hv6, mv2 + pv8, a1);
    a1 = fmaf(hv7, mv1 + pv9, a1);
    a2 = fmaf(hv0, mv9 + pv3, a2);
    a2 = fmaf(hv1, mv8 + pv4, a2);
    a2 = fmaf(hv2, mv7 + pv5, a2);
    a2 = fmaf(hv3, mv6 + pv6, a2);
    a2 = fmaf(hv4, mv5 + pv7, a2);
    a2 = fmaf(hv5, mv4 + pv8, a2);
    a2 = fmaf(hv6, mv3 + pv9, a2);
    a2 = fmaf(hv7, mv2 + pv10, a2);
    a3 = fmaf(hv0, mv10 + pv4, a3);
    a3 = fmaf(hv1, mv9 + pv5, a3);
    a3 = fmaf(hv2, mv8 + pv6, a3);
    a3 = fmaf(hv3, mv7 + pv7, a3);
    a3 = fmaf(hv4, mv6 + pv8, a3);
    a3 = fmaf(hv5, mv5 + pv9, a3);
    a3 = fmaf(hv6, mv4 + pv10, a3);
    a3 = fmaf(hv7, mv3 + pv11, a3);
  }
  int t = t0 + tid * 4;
  if (t < TAUD) {                     // TAUD%4==0 -> all 4 valid together
    float4 o = make_float4(a0 * 0.1f, a1 * 0.1f, a2 * 0.1f, a3 * 0.1f);
    *reinterpret_cast<float4*>(&ynz[(size_t)b * TAUD + t]) = o;
  }
}

// ---------------- final mix ----------------
__global__ __launch_bounds__(256) void k_final(const float* __restrict__ hpart,
                                               const float* __restrict__ ynz,
                                               const float* __restrict__ loud,
                                               float* __restrict__ out) {
  int idx = blockIdx.x * 256 + threadIdx.x;
  if (idx >= NBATCH * TAUD) return;
  int b = idx / TAUD, j = idx - b * TAUD;
  int i0, i1; float w;
  iparams(j, i0, i1, w);
  float env = __fadd_rn(__fmul_rn(loud[b * NT + i0], __fsub_rn(1.0f, w)),
                        __fmul_rn(loud[b * NT + i1], w));
  const size_t S = (size_t)NBATCH * TAUD;
  float hsum = __fadd_rn(__fadd_rn(__fadd_rn(hpart[idx], hpart[S + idx]),
                                   hpart[2 * S + idx]),
                         hpart[3 * S + idx]);
  out[idx] = __fmul_rn(__fadd_rn(hsum, ynz[idx]), env);
}

}  // namespace

extern "C" void kernel_launch(void* const* d_in, const int* in_sizes, int n_in,
                              void* d_out, int out_size, void* d_ws, size_t ws_size,
                              hipStream_t stream) {
  const float* z    = (const float*)d_in[0];
  const float* f0n  = (const float*)d_in[1];
  const float* loud = (const float*)d_in[2];
  const float* nz   = (const float*)d_in[3];
  const float* W1p  = (const float*)d_in[4];
  const float* b1p  = (const float*)d_in[5];
  const float* W2p  = (const float*)d_in[6];
  const float* b2p  = (const float*)d_in[7];
  const float* W1n  = (const float*)d_in[8];
  const float* b1n  = (const float*)d_in[9];
  const float* W2n  = (const float*)d_in[10];
  const float* b2n  = (const float*)d_in[11];
  float* out = (float*)d_out;
  float* ws  = (float*)d_ws;

  size_t off = 0;
  float* amp   = ws + off; off += (size_t)NBATCH * NT * NPART;      // 256,000
  float* nmag  = ws + off; off += (size_t)NBATCH * NT * NBINS;      // 1,024,000
  float* f0hz  = ws + off; off += (size_t)NBATCH * NT;              // 4,000
  float* mmw   = ws + off; off += (size_t)NBATCH * NBINS;           // 2,048
  float* G     = ws + off; off += (size_t)(LCONV + 1) * NBINS;      // 65,792
  float* hh    = ws + off; off += (size_t)NBATCH * (LCONV + 1);     // 2,056
  float* ynz   = ws + off; off += (size_t)NBATCH * TAUD;            // 704,000
  float* pref4 = ws + off; off += (size_t)NBATCH * NPART * 5500;    // 2,816,000
  float* hpart = ws + off; off += (size_t)4 * NBATCH * TAUD;        // 2,816,000
  (void)ws_size; (void)in_sizes; (void)n_in; (void)out_size;        // ~30 MB total

  double HI = log2(2093.0), LO = log2(32.7);
  float C1 = (float)(HI - LO), C2 = (float)LO;

  k_basis<<<LCONV + 1, 256, 0, stream>>>(G);
  k_f0<<<(NBATCH * NT + 255) / 256, 256, 0, stream>>>(f0n, f0hz, C1, C2);
  k_mlp<<<(NBATCH * NT) / MROWS, 256, 0, stream>>>(z, W1p, b1p, W2p, b2p,
                                                   W1n, b1n, W2n, b2n, amp, nmag);
  k_mean<<<NBATCH, 256, 0, stream>>>(nmag, mmw);
  k_hc<<<LCONV + 1, 256, 0, stream>>>(mmw, G, hh);
  k_scan_top<<<NBATCH * NPART, 256, 0, stream>>>(f0hz, pref4);
  dim3 gh(22, NBATCH, 4);
  k_harm<<<gh, 256, 0, stream>>>(f0hz, amp, pref4, hpart);
  dim3 gc((TAUD + CT - 1) / CT, NBATCH);
  k_conv<<<gc, 256, 0, stream>>>(nz, hh, ynz);
  k_final<<<(NBATCH * TAUD + 255) / 256, 256, 0, stream>>>(hpart, ynz, loud, out);
}